// Round 10
// baseline (380.269 us; speedup 1.0000x reference)
//
#include <hip/hip_runtime.h>
#include <hip/hip_fp16.h>

#define N_NODES 50000
#define N_EDGES 800000
#define D 128
#define ND (N_NODES * D)
#define BN_EPS 1e-5f

// bucketed CSR build
#define NB 256      // coarse buckets
#define NPB 196     // nodes per bucket (256*196 = 50176 >= 50000)
#define BCAP 4096   // max edges per bucket (mean 3136, sigma 56 -> 17 sigma headroom)

typedef short bf16x8 __attribute__((ext_vector_type(8)));
typedef _Float16 f16x8 __attribute__((ext_vector_type(8)));
typedef float f32x4 __attribute__((ext_vector_type(4)));
typedef unsigned short u16x8 __attribute__((ext_vector_type(8)));

__device__ inline unsigned short f2bf(float f) {
    unsigned int u = __float_as_uint(f);
    u += 0x7FFF + ((u >> 16) & 1);
    return (unsigned short)(u >> 16);
}
__device__ inline float bf2f(unsigned short h) {
    return __uint_as_float(((unsigned int)h) << 16);
}
__device__ inline unsigned short f2h(float f) {
    return __half_as_ushort(__float2half(f));
}
__device__ inline float h2f(unsigned short u) {
    return __half2float(__ushort_as_half(u));
}
__device__ inline f16x8 as_f16x8(u16x8 v) {
    union { u16x8 u; f16x8 f; } x; x.u = v; return x.f;
}
__device__ inline bf16x8 as_bf16x8(u16x8 v) {
    union { u16x8 u; bf16x8 f; } x; x.u = v; return x.f;
}

// ---------------------------------------------------------------------------
// Convert x (fp32) -> fp16
// ---------------------------------------------------------------------------
__global__ void convert_x(const float* __restrict__ x, ushort* __restrict__ xh) {
    int i = (blockIdx.x * blockDim.x + threadIdx.x) * 4;
    if (i < ND) {
        float4 v = *(const float4*)(x + i);
        *(ushort4*)(xh + i) = make_ushort4(f2h(v.x), f2h(v.y), f2h(v.z), f2h(v.w));
    }
}

// ---------------------------------------------------------------------------
// Pack 7 weight matrices [128x128] fp32 into MFMA B-fragment pairs.
// m < 6  (W1, W2 layers): fp16 hi + fp16((v-hi)*2048) lo -> 2-chain f16 MFMA
// m == 6 (Wp):            split-bf16 hi/lo -> 3-term bf16 MFMA (bn_proj)
// ---------------------------------------------------------------------------
__global__ void pack_w_split(const float* __restrict__ W1s, const float* __restrict__ W2s,
                             const float* __restrict__ Wp, ushort* __restrict__ out) {
    int idx = blockIdx.x * blockDim.x + threadIdx.x;
    if (idx >= 7 * 16384) return;
    int m = idx >> 14;
    int p = idx & 16383;
    int c = p >> 11;
    int kc = (p >> 9) & 3;
    int lane = (p >> 3) & 63;
    int j = p & 7;
    int k = kc * 32 + (lane >> 4) * 8 + j;
    int col = c * 16 + (lane & 15);
    const float* src = (m < 3) ? (W1s + (size_t)m * 16384)
                     : (m < 6) ? (W2s + (size_t)(m - 3) * 16384)
                               : Wp;
    float v = src[k * 128 + col];
    if (m < 6) {
        unsigned short hi = f2h(v);
        float r = (v - h2f(hi)) * 2048.0f;
        out[(size_t)(2 * m) * 16384 + p] = hi;
        out[(size_t)(2 * m + 1) * 16384 + p] = f2h(r);
    } else {
        unsigned short hi = f2bf(v);
        float r = v - bf2f(hi);
        out[(size_t)(2 * m) * 16384 + p] = hi;
        out[(size_t)(2 * m + 1) * 16384 + p] = f2bf(r);
    }
}

// ---------------------------------------------------------------------------
// CSR build step 1: per-block LDS histogram of coarse buckets -> global counts
// ---------------------------------------------------------------------------
__global__ __launch_bounds__(256) void bhist_kernel(const int* __restrict__ dst,
                                                    int* __restrict__ gbcnt) {
    __shared__ int cnt[NB];
    int tid = threadIdx.x;
    cnt[tid] = 0;
    __syncthreads();
    int base = blockIdx.x * 2048;
    #pragma unroll
    for (int k = 0; k < 8; ++k) {
        int e = base + k * 256 + tid;
        if (e < N_EDGES) atomicAdd(&cnt[dst[e] / NPB], 1);
    }
    __syncthreads();
    int c = cnt[tid];
    if (c > 0) atomicAdd(&gbcnt[tid], c);
}

// ---------------------------------------------------------------------------
// CSR build step 2: exclusive scan of the 256 bucket counts (one tiny block).
// ---------------------------------------------------------------------------
__global__ __launch_bounds__(256) void bscan_kernel(const int* __restrict__ gbcnt,
                                                    int* __restrict__ bstart,
                                                    int* __restrict__ bcur) {
    __shared__ int s[NB];
    int tid = threadIdx.x;
    int v = gbcnt[tid];
    s[tid] = v;
    __syncthreads();
    for (int d = 1; d < NB; d <<= 1) {
        int t = (tid >= d) ? s[tid - d] : 0;
        __syncthreads();
        s[tid] += t;
        __syncthreads();
    }
    int incl = s[tid];
    bstart[tid] = incl - v;
    bcur[tid] = incl - v;
    if (tid == NB - 1) bstart[NB] = incl;
}

// ---------------------------------------------------------------------------
// CSR build step 3a: coarse bucket scatter.
// ---------------------------------------------------------------------------
__global__ __launch_bounds__(256) void bucket_scatter(
    const int* __restrict__ src, const int* __restrict__ dst,
    const float* __restrict__ ew, int* __restrict__ bcur,
    uint2* __restrict__ pay) {
    __shared__ int cnt[NB];
    __shared__ int cur[NB];
    int tid = threadIdx.x;
    for (int i = tid; i < NB; i += 256) cnt[i] = 0;
    __syncthreads();
    int base = blockIdx.x * 2048;
    int s[8], d[8], b[8];
    float w[8];
    #pragma unroll
    for (int k = 0; k < 8; ++k) {
        int e = base + k * 256 + tid;
        bool v = e < N_EDGES;
        d[k] = v ? dst[e] : 0;
        s[k] = v ? src[e] : 0;
        w[k] = v ? ew[e] : 0.f;
        b[k] = d[k] / NPB;                 // constant div -> magic mul
        if (v) atomicAdd(&cnt[b[k]], 1);
    }
    __syncthreads();
    for (int i = tid; i < NB; i += 256) {
        int c = cnt[i];
        cur[i] = (c > 0) ? atomicAdd(&bcur[i], c) : 0;
    }
    __syncthreads();
    #pragma unroll
    for (int k = 0; k < 8; ++k) {
        int e = base + k * 256 + tid;
        if (e < N_EDGES) {
            int bk = b[k];
            int p = atomicAdd(&cur[bk], 1);
            unsigned dloc = (unsigned)(d[k] - bk * NPB);
            pay[p] = make_uint2((unsigned)s[k] | (dloc << 17), __float_as_uint(w[k]));
        }
    }
}

// ---------------------------------------------------------------------------
// CSR build step 3b: per-bucket exact sort, in place; also writes offs.
// ---------------------------------------------------------------------------
__global__ __launch_bounds__(256) void bucket_sort(const int* __restrict__ bstart,
                                                   int* __restrict__ offs,
                                                   uint2* __restrict__ pay) {
    __shared__ uint2 lp[BCAP];
    __shared__ int lcnt[NB];
    __shared__ int cur[NPB];
    int b = blockIdx.x;
    int tid = threadIdx.x;
    int n0 = b * NPB;
    int n1 = min(n0 + NPB, N_NODES);
    int nn = n1 - n0;
    int r0 = bstart[b];
    int r1 = bstart[b + 1];
    int cnt = r1 - r0;
    lcnt[tid] = 0;
    __syncthreads();
    for (int i = tid; i < cnt; i += 256) {
        uint2 e = pay[r0 + i];
        if (i < BCAP) lp[i] = e;
        atomicAdd(&lcnt[e.x >> 17], 1);
    }
    __syncthreads();
    int v = lcnt[tid];
    for (int d = 1; d < NB; d <<= 1) {
        int t = (tid >= d) ? lcnt[tid - d] : 0;
        __syncthreads();
        lcnt[tid] += t;
        __syncthreads();
    }
    int excl = lcnt[tid] - v;
    if (tid < nn) {
        offs[n0 + tid] = r0 + excl;
        cur[tid] = excl;
    }
    if (tid == 0) offs[n1] = r1;
    __syncthreads();
    for (int i = tid; i < cnt; i += 256) {
        if (i < BCAP) {
            uint2 e = lp[i];
            int p = atomicAdd(&cur[e.x >> 17], 1);
            if (p < BCAP) pay[r0 + p] = make_uint2(e.x & 0x1FFFFu, e.y);
        }
    }
}

// ---------------------------------------------------------------------------
// Gather-aggregate + GIN combine (fp16 in, fp32 accumulate, fp16 out).
// 32 lanes/node (max TLP), edge loop unrolled x8 for memory-level parallelism.
// ---------------------------------------------------------------------------
__global__ void gather_agg_f16(const ushort* __restrict__ z, const int* __restrict__ offs,
                               const uint2* __restrict__ pay,
                               const float* __restrict__ epsp, int layer,
                               ushort* __restrict__ A) {
    int tid = blockIdx.x * blockDim.x + threadIdx.x;
    int n = tid >> 5;
    if (n >= N_NODES) return;
    int f = (tid & 31) << 2;
    float epsv = 1.0f + epsp[layer];
    int beg = offs[n], end = offs[n + 1];
    ushort4 zi = *(const ushort4*)(z + (size_t)n * D + f);
    float ax = epsv * h2f(zi.x), ay = epsv * h2f(zi.y);
    float az = epsv * h2f(zi.z), aw = epsv * h2f(zi.w);
    int j = beg;
    for (; j + 8 <= end; j += 8) {
        uint2 e[8];
        #pragma unroll
        for (int k = 0; k < 8; ++k) e[k] = pay[j + k];
        ushort4 v[8];
        #pragma unroll
        for (int k = 0; k < 8; ++k) v[k] = *(const ushort4*)(z + (size_t)e[k].x * D + f);
        #pragma unroll
        for (int k = 0; k < 8; ++k) {
            float w = __uint_as_float(e[k].y);
            ax += h2f(v[k].x) * w; ay += h2f(v[k].y) * w;
            az += h2f(v[k].z) * w; aw += h2f(v[k].w) * w;
        }
    }
    for (; j + 4 <= end; j += 4) {
        uint2 e0 = pay[j];
        uint2 e1 = pay[j + 1];
        uint2 e2 = pay[j + 2];
        uint2 e3 = pay[j + 3];
        ushort4 v0 = *(const ushort4*)(z + (size_t)e0.x * D + f);
        ushort4 v1 = *(const ushort4*)(z + (size_t)e1.x * D + f);
        ushort4 v2 = *(const ushort4*)(z + (size_t)e2.x * D + f);
        ushort4 v3 = *(const ushort4*)(z + (size_t)e3.x * D + f);
        float w0 = __uint_as_float(e0.y);
        float w1 = __uint_as_float(e1.y);
        float w2 = __uint_as_float(e2.y);
        float w3 = __uint_as_float(e3.y);
        ax += h2f(v0.x) * w0 + h2f(v1.x) * w1 + h2f(v2.x) * w2 + h2f(v3.x) * w3;
        ay += h2f(v0.y) * w0 + h2f(v1.y) * w1 + h2f(v2.y) * w2 + h2f(v3.y) * w3;
        az += h2f(v0.z) * w0 + h2f(v1.z) * w1 + h2f(v2.z) * w2 + h2f(v3.z) * w3;
        aw += h2f(v0.w) * w0 + h2f(v1.w) * w1 + h2f(v2.w) * w2 + h2f(v3.w) * w3;
    }
    for (; j < end; ++j) {
        uint2 e0 = pay[j];
        ushort4 v0 = *(const ushort4*)(z + (size_t)e0.x * D + f);
        float w0 = __uint_as_float(e0.y);
        ax += h2f(v0.x) * w0; ay += h2f(v0.y) * w0;
        az += h2f(v0.z) * w0; aw += h2f(v0.w) * w0;
    }
    *(ushort4*)(A + (size_t)n * D + f) = make_ushort4(f2h(ax), f2h(ay), f2h(az), f2h(aw));
}

// ---------------------------------------------------------------------------
// Fused GIN MLP — 32-row blocks for 2x grid occupancy (782 -> 1563 blocks,
// ~6 blocks/CU; the grid was the occupancy cap at 64 rows).
// c-split: 4 waves; wave w owns col-groups {2w,2w+1} for both 16-row frags.
// GEMM1 & GEMM2: 2-chain f16 MFMA (W = f16 hi + 2048-scaled f16 lo).
// H in LDS as plain fp16 (8.7 KB/block).
// ---------------------------------------------------------------------------
#define HSTR2 136   // ushorts: 128 + 8 pad -> 272B row stride
template<bool STATS>
__global__ __launch_bounds__(256) void mlp_fused(
    const ushort* __restrict__ A,
    const ushort* __restrict__ W1hi, const ushort* __restrict__ W1lo,
    const float* __restrict__ b1,
    const ushort* __restrict__ W2hi, const ushort* __restrict__ W2lo,
    const float* __restrict__ b2, ushort* __restrict__ Z,
    float* __restrict__ stats) {
    __shared__ ushort Hs[32 * HSTR2];
    int tid = threadIdx.x;
    int lane = tid & 63;
    int wave = tid >> 6;
    int rlo = lane & 15;
    int quad = lane >> 4;
    int blk0 = blockIdx.x * 32;

    const f16x8* W1h = (const f16x8*)W1hi;
    const f16x8* W1l = (const f16x8*)W1lo;
    const f16x8* W2h = (const f16x8*)W2hi;
    const f16x8* W2l = (const f16x8*)W2lo;

    // A fragments for both 16-row frags (all waves load the same tile -> L1)
    f16x8 af[2][4];
    #pragma unroll
    for (int rf = 0; rf < 2; ++rf) {
        int arow = blk0 + rf * 16 + rlo;
        int ar = (arow < N_NODES) ? arow : (N_NODES - 1);
        #pragma unroll
        for (int kc = 0; kc < 4; ++kc) {
            u16x8 raw = *(const u16x8*)(A + (size_t)ar * D + kc * 32 + quad * 8);
            af[rf][kc] = as_f16x8(raw);
        }
    }

    // GEMM1: wave computes its 2 column-groups for both row-frags;
    // epilogue-1 stores H as plain f16 to LDS.
    #pragma unroll
    for (int cc = 0; cc < 2; ++cc) {
        int c = 2 * wave + cc;
        f32x4 aH[2], aL[2];
        #pragma unroll
        for (int rf = 0; rf < 2; ++rf) {
            aH[rf] = (f32x4){0.f, 0.f, 0.f, 0.f};
            aL[rf] = (f32x4){0.f, 0.f, 0.f, 0.f};
        }
        #pragma unroll
        for (int kc = 0; kc < 4; ++kc) {
            f16x8 wh = W1h[(c * 4 + kc) * 64 + lane];
            f16x8 wl = W1l[(c * 4 + kc) * 64 + lane];
            #pragma unroll
            for (int rf = 0; rf < 2; ++rf) {
                aH[rf] = __builtin_amdgcn_mfma_f32_16x16x32_f16(af[rf][kc], wh, aH[rf], 0, 0, 0);
                aL[rf] = __builtin_amdgcn_mfma_f32_16x16x32_f16(af[rf][kc], wl, aL[rf], 0, 0, 0);
            }
        }
        int col = c * 16 + rlo;
        float bb = b1[col];
        #pragma unroll
        for (int rf = 0; rf < 2; ++rf) {
            #pragma unroll
            for (int r = 0; r < 4; ++r) {
                float v = fmaxf(aH[rf][r] + aL[rf][r] * (1.0f / 2048.0f) + bb, 0.f);
                Hs[(rf * 16 + quad * 4 + r) * HSTR2 + col] = f2h(v);
            }
        }
    }
    __syncthreads();

    // GEMM2: 2-chain f16 (A2 fragments straight from LDS, exact f16)
    f32x4 aH2[2][2], aL2[2][2];
    #pragma unroll
    for (int cc = 0; cc < 2; ++cc)
        #pragma unroll
        for (int rf = 0; rf < 2; ++rf) {
            aH2[cc][rf] = (f32x4){0.f, 0.f, 0.f, 0.f};
            aL2[cc][rf] = (f32x4){0.f, 0.f, 0.f, 0.f};
        }

    #pragma unroll
    for (int kc = 0; kc < 4; ++kc) {
        f16x8 a2[2];
        #pragma unroll
        for (int rf = 0; rf < 2; ++rf) {
            a2[rf] = as_f16x8(*(const u16x8*)&Hs[(rf * 16 + rlo) * HSTR2 + kc * 32 + quad * 8]);
        }
        #pragma unroll
        for (int cc = 0; cc < 2; ++cc) {
            int c = 2 * wave + cc;
            f16x8 wh = W2h[(c * 4 + kc) * 64 + lane];
            f16x8 wl = W2l[(c * 4 + kc) * 64 + lane];
            #pragma unroll
            for (int rf = 0; rf < 2; ++rf) {
                aH2[cc][rf] = __builtin_amdgcn_mfma_f32_16x16x32_f16(a2[rf], wh, aH2[cc][rf], 0, 0, 0);
                aL2[cc][rf] = __builtin_amdgcn_mfma_f32_16x16x32_f16(a2[rf], wl, aL2[cc][rf], 0, 0, 0);
            }
        }
    }
    __syncthreads();   // all LDS reads done before epilogue-2 overwrites

    // epilogue 2: relu(acc + b2) -> fp16 in Hs, fused stats (fp32 pre-round)
    #pragma unroll
    for (int cc = 0; cc < 2; ++cc) {
        int c = 2 * wave + cc;
        int col = c * 16 + rlo;
        float bb = b2[col];
        float s = 0.f, s2 = 0.f;
        #pragma unroll
        for (int rf = 0; rf < 2; ++rf) {
            #pragma unroll
            for (int r = 0; r < 4; ++r) {
                float v = fmaxf(aH2[cc][rf][r] + aL2[cc][rf][r] * (1.0f / 2048.0f) + bb, 0.f);
                Hs[(rf * 16 + quad * 4 + r) * HSTR2 + col] = f2h(v);
                if (STATS) {
                    float m = (blk0 + rf * 16 + quad * 4 + r < N_NODES) ? v : 0.f;
                    s += m;
                    s2 += m * m;
                }
            }
        }
        if (STATS) {
            s  += __shfl_xor(s, 16, 64);
            s  += __shfl_xor(s, 32, 64);
            s2 += __shfl_xor(s2, 16, 64);
            s2 += __shfl_xor(s2, 32, 64);
            if (quad == 0) {
                atomicAdd(&stats[col], s);
                atomicAdd(&stats[D + col], s2);
            }
        }
    }
    __syncthreads();

    // coalesced fp16 copy-out: wave w writes rows [8w, 8w+8)
    #pragma unroll
    for (int it = 0; it < 2; ++it) {
        int r = wave * 8 + it * 4 + quad;
        int grow = blk0 + r;
        if (grow < N_NODES) {
            u16x8 vv = *(const u16x8*)&Hs[r * HSTR2 + rlo * 8];
            *(u16x8*)(Z + (size_t)grow * D + rlo * 8) = vv;
        }
    }
}

// ---------------------------------------------------------------------------
// Final: zn = BN(Z)*gamma+beta (fp32 out), p = PReLU(zn @ Wp + bp) (fp32 out)
// ---------------------------------------------------------------------------
#define PSTR 132   // floats
__global__ __launch_bounds__(256) void bn_proj(
    const ushort* __restrict__ Z, const float* __restrict__ stats,
    const float* __restrict__ gamma, const float* __restrict__ beta,
    const ushort* __restrict__ Wphi, const ushort* __restrict__ Wplo,
    const float* __restrict__ bp, const float* __restrict__ prelu_a,
    float* __restrict__ zn_out, float* __restrict__ p_out) {
    __shared__ float sc_s[D];
    __shared__ float sh_s[D];
    __shared__ float Ps[4][16 * PSTR];
    int tid = threadIdx.x;
    int lane = tid & 63;
    int wave = tid >> 6;
    int rlo = lane & 15;
    int quad = lane >> 4;

    if (tid < D) {
        float m = stats[tid] * (1.0f / N_NODES);
        float v = stats[D + tid] * (1.0f / N_NODES) - m * m;
        float rs = rsqrtf(v + BN_EPS);
        float sc = rs * gamma[tid];
        sc_s[tid] = sc;
        sh_s[tid] = beta[tid] - m * sc;
    }
    __syncthreads();

    int row0 = blockIdx.x * 64 + wave * 16;
    int arow = row0 + rlo;
    int ar = (arow < N_NODES) ? arow : (N_NODES - 1);

    const bf16x8* Wh = (const bf16x8*)Wphi;
    const bf16x8* Wl = (const bf16x8*)Wplo;

    // load Z frags, apply BN -> zn (fp32 store + split-bf16 a-frags)
    bf16x8 ahi[4], alo[4];
    #pragma unroll
    for (int kc = 0; kc < 4; ++kc) {
        u16x8 raw = *(const u16x8*)(Z + (size_t)ar * D + kc * 32 + quad * 8);
        float zn[8];
        #pragma unroll
        for (int j = 0; j < 8; ++j) {
            int k = kc * 32 + quad * 8 + j;
            zn[j] = sc_s[k] * h2f(raw[j]) + sh_s[k];
            unsigned short h = f2bf(zn[j]);
            ahi[kc][j] = (short)h;
            alo[kc][j] = (short)f2bf(zn[j] - bf2f(h));
        }
        if (arow < N_NODES) {
            float* dst = zn_out + (size_t)arow * D + kc * 32 + quad * 8;
            *(float4*)dst = make_float4(zn[0], zn[1], zn[2], zn[3]);
            *(float4*)(dst + 4) = make_float4(zn[4], zn[5], zn[6], zn[7]);
        }
    }

    f32x4 acc[8];
    #pragma unroll
    for (int c = 0; c < 8; ++c) acc[c] = (f32x4){0.f, 0.f, 0.f, 0.f};
    #pragma unroll
    for (int c = 0; c < 8; ++c) {
        #pragma unroll
        for (int kc = 0; kc < 4; ++kc) {
            bf16x8 wh = Wh[(c * 4 + kc) * 64 + lane];
            bf16x8 wl = Wl[(c * 4 + kc) * 64 + lane];
            acc[c] = __builtin_amdgcn_mfma_f32_16x16x32_bf16(alo[kc], wh, acc[c], 0, 0, 0);
            acc[c] = __builtin_amdgcn_mfma_f32_16x16x32_bf16(ahi[kc], wl, acc[c], 0, 0, 0);
            acc[c] = __builtin_amdgcn_mfma_f32_16x16x32_bf16(ahi[kc], wh, acc[c], 0, 0, 0);
        }
    }

    float aP = prelu_a[0];
    #pragma unroll
    for (int c = 0; c < 8; ++c) {
        int col = c * 16 + rlo;
        float bb = bp[col];
        #pragma unroll
        for (int r = 0; r < 4; ++r) {
            float v = acc[c][r] + bb;
            v = (v >= 0.f) ? v : aP * v;
            Ps[wave][(quad * 4 + r) * PSTR + col] = v;
        }
    }
    __syncthreads();
    #pragma unroll
    for (int p2 = 0; p2 < 8; ++p2) {
        int r = p2 * 2 + (lane >> 5);
        int grow = row0 + r;
        if (grow < N_NODES) {
            *(float4*)(p_out + (size_t)grow * D + (lane & 31) * 4) =
                *(const float4*)&Ps[wave][r * PSTR + (lane & 31) * 4];
        }
    }
}

// ---------------------------------------------------------------------------
extern "C" void kernel_launch(void* const* d_in, const int* in_sizes, int n_in,
                              void* d_out, int out_size, void* d_ws, size_t ws_size,
                              hipStream_t stream) {
    (void)in_sizes; (void)n_in; (void)out_size; (void)ws_size;
    const float* x     = (const float*)d_in[0];
    const float* ew    = (const float*)d_in[1];
    const float* W1s   = (const float*)d_in[2];
    const float* b1s   = (const float*)d_in[3];
    const float* W2s   = (const float*)d_in[4];
    const float* b2s   = (const float*)d_in[5];
    const float* eps   = (const float*)d_in[6];
    const float* gamma = (const float*)d_in[7];
    const float* beta  = (const float*)d_in[8];
    const float* Wp    = (const float*)d_in[9];
    const float* bp    = (const float*)d_in[10];
    const float* pa    = (const float*)d_in[11];
    const int*   ei    = (const int*)d_in[12];
    const int* srcp = ei;
    const int* dstp = ei + N_EDGES;

    // workspace layout (bytes):
    char* wsb = (char*)d_ws;
    float*  stats  = (float*)wsb;                 wsb += 1024;           // 256 f
    int*    offs   = (int*)wsb;                   wsb += 200016;         // 50004 i
    int*    bcur   = (int*)wsb;                   // 256 i
    int*    gbcnt  = bcur + 256;                  // 256 i
    int*    bstart = bcur + 512;                  wsb += 200016;         // 257 i
    uint2*  pay    = (uint2*)wsb;                 wsb += 6400000;        // 800000 uint2
    ushort* Wpk    = (ushort*)wsb;                wsb += 14 * 16384 * 2; // split weights
    ushort* Xh     = (ushort*)wsb;                wsb += (size_t)ND * 2; // x in fp16
    ushort* Ah     = (ushort*)wsb;                wsb += (size_t)ND * 2; // gather out fp16
    ushort* Zh     = (ushort*)wsb;                wsb += (size_t)ND * 2; // layer out fp16

    float* out_zn = (float*)d_out;
    float* out_p  = out_zn + ND;

    hipMemsetAsync(stats, 0, 256 * sizeof(float), stream);
    hipMemsetAsync(gbcnt, 0, NB * sizeof(int), stream);

    convert_x<<<(ND / 4 + 255) / 256, 256, 0, stream>>>(x, Xh);
    pack_w_split<<<(7 * 16384 + 255) / 256, 256, 0, stream>>>(W1s, W2s, Wp, Wpk);

    bhist_kernel<<<(N_EDGES + 2047) / 2048, 256, 0, stream>>>(dstp, gbcnt);
    bscan_kernel<<<1, 256, 0, stream>>>(gbcnt, bstart, bcur);
    bucket_scatter<<<(N_EDGES + 2047) / 2048, 256, 0, stream>>>(srcp, dstp, ew, bcur, pay);
    bucket_sort<<<NB, 256, 0, stream>>>(bstart, offs, pay);

    int mgrid = (N_NODES + 31) / 32;     // 32-row blocks: 1563 blocks, ~6/CU
    int pgrid = (N_NODES + 63) / 64;
    const ushort* zin = Xh;
    for (int l = 0; l < 3; ++l) {
        gather_agg_f16<<<(N_NODES * 32 + 255) / 256, 256, 0, stream>>>(zin, offs, pay, eps, l, Ah);
        if (l < 2) {
            mlp_fused<false><<<mgrid, 256, 0, stream>>>(Ah,
                Wpk + (size_t)(2 * l) * 16384,       Wpk + (size_t)(2 * l + 1) * 16384, b1s + (size_t)l * D,
                Wpk + (size_t)(2 * (3 + l)) * 16384, Wpk + (size_t)(2 * (3 + l) + 1) * 16384, b2s + (size_t)l * D,
                Zh, stats);
        } else {
            mlp_fused<true><<<mgrid, 256, 0, stream>>>(Ah,
                Wpk + (size_t)(2 * l) * 16384,       Wpk + (size_t)(2 * l + 1) * 16384, b1s + (size_t)l * D,
                Wpk + (size_t)(2 * (3 + l)) * 16384, Wpk + (size_t)(2 * (3 + l) + 1) * 16384, b2s + (size_t)l * D,
                Zh, stats);
        }
        zin = Zh;
    }
    bn_proj<<<pgrid, 256, 0, stream>>>(Zh, stats, gamma, beta,
        Wpk + (size_t)12 * 16384, Wpk + (size_t)13 * 16384, bp, pa, out_zn, out_p);
}

// Round 11
// 369.356 us; speedup vs baseline: 1.0295x; 1.0295x over previous
//
#include <hip/hip_runtime.h>
#include <hip/hip_fp16.h>

#define N_NODES 50000
#define N_EDGES 800000
#define D 128
#define ND (N_NODES * D)
#define BN_EPS 1e-5f

// bucketed CSR build
#define NB 256      // coarse buckets
#define NPB 196     // nodes per bucket (256*196 = 50176 >= 50000)
#define BCAP 4096   // max edges per bucket (mean 3136, sigma 56 -> 17 sigma headroom)

typedef short bf16x8 __attribute__((ext_vector_type(8)));
typedef _Float16 f16x8 __attribute__((ext_vector_type(8)));
typedef float f32x4 __attribute__((ext_vector_type(4)));
typedef unsigned short u16x8 __attribute__((ext_vector_type(8)));

__device__ inline unsigned short f2bf(float f) {
    unsigned int u = __float_as_uint(f);
    u += 0x7FFF + ((u >> 16) & 1);
    return (unsigned short)(u >> 16);
}
__device__ inline float bf2f(unsigned short h) {
    return __uint_as_float(((unsigned int)h) << 16);
}
__device__ inline unsigned short f2h(float f) {
    return __half_as_ushort(__float2half(f));
}
__device__ inline float h2f(unsigned short u) {
    return __half2float(__ushort_as_half(u));
}
__device__ inline f16x8 as_f16x8(u16x8 v) {
    union { u16x8 u; f16x8 f; } x; x.u = v; return x.f;
}
__device__ inline bf16x8 as_bf16x8(u16x8 v) {
    union { u16x8 u; bf16x8 f; } x; x.u = v; return x.f;
}

// ---------------------------------------------------------------------------
// Convert x (fp32) -> fp16
// ---------------------------------------------------------------------------
__global__ void convert_x(const float* __restrict__ x, ushort* __restrict__ xh) {
    int i = (blockIdx.x * blockDim.x + threadIdx.x) * 4;
    if (i < ND) {
        float4 v = *(const float4*)(x + i);
        *(ushort4*)(xh + i) = make_ushort4(f2h(v.x), f2h(v.y), f2h(v.z), f2h(v.w));
    }
}

// ---------------------------------------------------------------------------
// Pack 7 weight matrices [128x128] fp32 into MFMA B-fragment pairs.
// m < 6  (W1, W2 layers): fp16 hi + fp16((v-hi)*2048) lo -> 2-chain f16 MFMA
// m == 6 (Wp):            split-bf16 hi/lo -> 3-term bf16 MFMA (bn_proj)
// ---------------------------------------------------------------------------
__global__ void pack_w_split(const float* __restrict__ W1s, const float* __restrict__ W2s,
                             const float* __restrict__ Wp, ushort* __restrict__ out) {
    int idx = blockIdx.x * blockDim.x + threadIdx.x;
    if (idx >= 7 * 16384) return;
    int m = idx >> 14;
    int p = idx & 16383;
    int c = p >> 11;
    int kc = (p >> 9) & 3;
    int lane = (p >> 3) & 63;
    int j = p & 7;
    int k = kc * 32 + (lane >> 4) * 8 + j;
    int col = c * 16 + (lane & 15);
    const float* src = (m < 3) ? (W1s + (size_t)m * 16384)
                     : (m < 6) ? (W2s + (size_t)(m - 3) * 16384)
                               : Wp;
    float v = src[k * 128 + col];
    if (m < 6) {
        unsigned short hi = f2h(v);
        float r = (v - h2f(hi)) * 2048.0f;
        out[(size_t)(2 * m) * 16384 + p] = hi;
        out[(size_t)(2 * m + 1) * 16384 + p] = f2h(r);
    } else {
        unsigned short hi = f2bf(v);
        float r = v - bf2f(hi);
        out[(size_t)(2 * m) * 16384 + p] = hi;
        out[(size_t)(2 * m + 1) * 16384 + p] = f2bf(r);
    }
}

// ---------------------------------------------------------------------------
// CSR build step 1: per-block LDS histogram of coarse buckets -> global counts
// ---------------------------------------------------------------------------
__global__ __launch_bounds__(256) void bhist_kernel(const int* __restrict__ dst,
                                                    int* __restrict__ gbcnt) {
    __shared__ int cnt[NB];
    int tid = threadIdx.x;
    cnt[tid] = 0;
    __syncthreads();
    int base = blockIdx.x * 2048;
    #pragma unroll
    for (int k = 0; k < 8; ++k) {
        int e = base + k * 256 + tid;
        if (e < N_EDGES) atomicAdd(&cnt[dst[e] / NPB], 1);
    }
    __syncthreads();
    int c = cnt[tid];
    if (c > 0) atomicAdd(&gbcnt[tid], c);
}

// ---------------------------------------------------------------------------
// CSR build step 2: exclusive scan of the 256 bucket counts (one tiny block).
// ---------------------------------------------------------------------------
__global__ __launch_bounds__(256) void bscan_kernel(const int* __restrict__ gbcnt,
                                                    int* __restrict__ bstart,
                                                    int* __restrict__ bcur) {
    __shared__ int s[NB];
    int tid = threadIdx.x;
    int v = gbcnt[tid];
    s[tid] = v;
    __syncthreads();
    for (int d = 1; d < NB; d <<= 1) {
        int t = (tid >= d) ? s[tid - d] : 0;
        __syncthreads();
        s[tid] += t;
        __syncthreads();
    }
    int incl = s[tid];
    bstart[tid] = incl - v;
    bcur[tid] = incl - v;
    if (tid == NB - 1) bstart[NB] = incl;
}

// ---------------------------------------------------------------------------
// CSR build step 3a: coarse bucket scatter.
// ---------------------------------------------------------------------------
__global__ __launch_bounds__(256) void bucket_scatter(
    const int* __restrict__ src, const int* __restrict__ dst,
    const float* __restrict__ ew, int* __restrict__ bcur,
    uint2* __restrict__ pay) {
    __shared__ int cnt[NB];
    __shared__ int cur[NB];
    int tid = threadIdx.x;
    for (int i = tid; i < NB; i += 256) cnt[i] = 0;
    __syncthreads();
    int base = blockIdx.x * 2048;
    int s[8], d[8], b[8];
    float w[8];
    #pragma unroll
    for (int k = 0; k < 8; ++k) {
        int e = base + k * 256 + tid;
        bool v = e < N_EDGES;
        d[k] = v ? dst[e] : 0;
        s[k] = v ? src[e] : 0;
        w[k] = v ? ew[e] : 0.f;
        b[k] = d[k] / NPB;                 // constant div -> magic mul
        if (v) atomicAdd(&cnt[b[k]], 1);
    }
    __syncthreads();
    for (int i = tid; i < NB; i += 256) {
        int c = cnt[i];
        cur[i] = (c > 0) ? atomicAdd(&bcur[i], c) : 0;
    }
    __syncthreads();
    #pragma unroll
    for (int k = 0; k < 8; ++k) {
        int e = base + k * 256 + tid;
        if (e < N_EDGES) {
            int bk = b[k];
            int p = atomicAdd(&cur[bk], 1);
            unsigned dloc = (unsigned)(d[k] - bk * NPB);
            pay[p] = make_uint2((unsigned)s[k] | (dloc << 17), __float_as_uint(w[k]));
        }
    }
}

// ---------------------------------------------------------------------------
// CSR build step 3b: per-bucket exact sort, in place; also writes offs.
// ---------------------------------------------------------------------------
__global__ __launch_bounds__(256) void bucket_sort(const int* __restrict__ bstart,
                                                   int* __restrict__ offs,
                                                   uint2* __restrict__ pay) {
    __shared__ uint2 lp[BCAP];
    __shared__ int lcnt[NB];
    __shared__ int cur[NPB];
    int b = blockIdx.x;
    int tid = threadIdx.x;
    int n0 = b * NPB;
    int n1 = min(n0 + NPB, N_NODES);
    int nn = n1 - n0;
    int r0 = bstart[b];
    int r1 = bstart[b + 1];
    int cnt = r1 - r0;
    lcnt[tid] = 0;
    __syncthreads();
    for (int i = tid; i < cnt; i += 256) {
        uint2 e = pay[r0 + i];
        if (i < BCAP) lp[i] = e;
        atomicAdd(&lcnt[e.x >> 17], 1);
    }
    __syncthreads();
    int v = lcnt[tid];
    for (int d = 1; d < NB; d <<= 1) {
        int t = (tid >= d) ? lcnt[tid - d] : 0;
        __syncthreads();
        lcnt[tid] += t;
        __syncthreads();
    }
    int excl = lcnt[tid] - v;
    if (tid < nn) {
        offs[n0 + tid] = r0 + excl;
        cur[tid] = excl;
    }
    if (tid == 0) offs[n1] = r1;
    __syncthreads();
    for (int i = tid; i < cnt; i += 256) {
        if (i < BCAP) {
            uint2 e = lp[i];
            int p = atomicAdd(&cur[e.x >> 17], 1);
            if (p < BCAP) pay[r0 + p] = make_uint2(e.x & 0x1FFFFu, e.y);
        }
    }
}

// ---------------------------------------------------------------------------
// Gather-aggregate + GIN combine (fp16 in, fp32 accumulate, fp16 out).
// 32 lanes/node (max TLP), edge loop unrolled x8 for memory-level parallelism.
// ---------------------------------------------------------------------------
__global__ void gather_agg_f16(const ushort* __restrict__ z, const int* __restrict__ offs,
                               const uint2* __restrict__ pay,
                               const float* __restrict__ epsp, int layer,
                               ushort* __restrict__ A) {
    int tid = blockIdx.x * blockDim.x + threadIdx.x;
    int n = tid >> 5;
    if (n >= N_NODES) return;
    int f = (tid & 31) << 2;
    float epsv = 1.0f + epsp[layer];
    int beg = offs[n], end = offs[n + 1];
    ushort4 zi = *(const ushort4*)(z + (size_t)n * D + f);
    float ax = epsv * h2f(zi.x), ay = epsv * h2f(zi.y);
    float az = epsv * h2f(zi.z), aw = epsv * h2f(zi.w);
    int j = beg;
    for (; j + 8 <= end; j += 8) {
        uint2 e[8];
        #pragma unroll
        for (int k = 0; k < 8; ++k) e[k] = pay[j + k];
        ushort4 v[8];
        #pragma unroll
        for (int k = 0; k < 8; ++k) v[k] = *(const ushort4*)(z + (size_t)e[k].x * D + f);
        #pragma unroll
        for (int k = 0; k < 8; ++k) {
            float w = __uint_as_float(e[k].y);
            ax += h2f(v[k].x) * w; ay += h2f(v[k].y) * w;
            az += h2f(v[k].z) * w; aw += h2f(v[k].w) * w;
        }
    }
    for (; j + 4 <= end; j += 4) {
        uint2 e0 = pay[j];
        uint2 e1 = pay[j + 1];
        uint2 e2 = pay[j + 2];
        uint2 e3 = pay[j + 3];
        ushort4 v0 = *(const ushort4*)(z + (size_t)e0.x * D + f);
        ushort4 v1 = *(const ushort4*)(z + (size_t)e1.x * D + f);
        ushort4 v2 = *(const ushort4*)(z + (size_t)e2.x * D + f);
        ushort4 v3 = *(const ushort4*)(z + (size_t)e3.x * D + f);
        float w0 = __uint_as_float(e0.y);
        float w1 = __uint_as_float(e1.y);
        float w2 = __uint_as_float(e2.y);
        float w3 = __uint_as_float(e3.y);
        ax += h2f(v0.x) * w0 + h2f(v1.x) * w1 + h2f(v2.x) * w2 + h2f(v3.x) * w3;
        ay += h2f(v0.y) * w0 + h2f(v1.y) * w1 + h2f(v2.y) * w2 + h2f(v3.y) * w3;
        az += h2f(v0.z) * w0 + h2f(v1.z) * w1 + h2f(v2.z) * w2 + h2f(v3.z) * w3;
        aw += h2f(v0.w) * w0 + h2f(v1.w) * w1 + h2f(v2.w) * w2 + h2f(v3.w) * w3;
    }
    for (; j < end; ++j) {
        uint2 e0 = pay[j];
        ushort4 v0 = *(const ushort4*)(z + (size_t)e0.x * D + f);
        float w0 = __uint_as_float(e0.y);
        ax += h2f(v0.x) * w0; ay += h2f(v0.y) * w0;
        az += h2f(v0.z) * w0; aw += h2f(v0.w) * w0;
    }
    *(ushort4*)(A + (size_t)n * D + f) = make_ushort4(f2h(ax), f2h(ay), f2h(az), f2h(aw));
}

// ---------------------------------------------------------------------------
// Fused GIN MLP — c-split, 64-row blocks (round-9 structure), with:
// * 2 barriers instead of 3: epilogue-2 writes a SECOND H buffer (Ho), so
//   there is no write-after-read hazard against GEMM2's Hs reads.
// * s_setprio(1) around the MFMA clusters (blocks are mutually async; CU
//   scheduler favors MFMA-phase waves over load-phase waves).
// GEMM1 & GEMM2: 2-chain f16 MFMA (W = f16 hi + 2048-scaled f16 lo).
// ---------------------------------------------------------------------------
#define HSTR2 136   // ushorts: 128 + 8 pad -> 272B row stride
template<bool STATS>
__global__ __launch_bounds__(256) void mlp_fused(
    const ushort* __restrict__ A,
    const ushort* __restrict__ W1hi, const ushort* __restrict__ W1lo,
    const float* __restrict__ b1,
    const ushort* __restrict__ W2hi, const ushort* __restrict__ W2lo,
    const float* __restrict__ b2, ushort* __restrict__ Z,
    float* __restrict__ stats) {
    __shared__ ushort Hs[64 * HSTR2];
    __shared__ ushort Ho[64 * HSTR2];
    int tid = threadIdx.x;
    int lane = tid & 63;
    int wave = tid >> 6;
    int rlo = lane & 15;
    int quad = lane >> 4;
    int blk0 = blockIdx.x * 64;

    const f16x8* W1h = (const f16x8*)W1hi;
    const f16x8* W1l = (const f16x8*)W1lo;
    const f16x8* W2h = (const f16x8*)W2hi;
    const f16x8* W2l = (const f16x8*)W2lo;

    // A fragments for all 4 row-frags (all waves load the same tile -> L1)
    f16x8 af[4][4];
    #pragma unroll
    for (int rf = 0; rf < 4; ++rf) {
        int arow = blk0 + rf * 16 + rlo;
        int ar = (arow < N_NODES) ? arow : (N_NODES - 1);
        #pragma unroll
        for (int kc = 0; kc < 4; ++kc) {
            u16x8 raw = *(const u16x8*)(A + (size_t)ar * D + kc * 32 + quad * 8);
            af[rf][kc] = as_f16x8(raw);
        }
    }

    // GEMM1: wave computes its 2 column-groups for all 4 row-frags;
    // epilogue-1 stores H as plain f16 to LDS.
    #pragma unroll
    for (int cc = 0; cc < 2; ++cc) {
        int c = 2 * wave + cc;
        f32x4 aH[4], aL[4];
        #pragma unroll
        for (int rf = 0; rf < 4; ++rf) {
            aH[rf] = (f32x4){0.f, 0.f, 0.f, 0.f};
            aL[rf] = (f32x4){0.f, 0.f, 0.f, 0.f};
        }
        __builtin_amdgcn_s_setprio(1);
        #pragma unroll
        for (int kc = 0; kc < 4; ++kc) {
            f16x8 wh = W1h[(c * 4 + kc) * 64 + lane];
            f16x8 wl = W1l[(c * 4 + kc) * 64 + lane];
            #pragma unroll
            for (int rf = 0; rf < 4; ++rf) {
                aH[rf] = __builtin_amdgcn_mfma_f32_16x16x32_f16(af[rf][kc], wh, aH[rf], 0, 0, 0);
                aL[rf] = __builtin_amdgcn_mfma_f32_16x16x32_f16(af[rf][kc], wl, aL[rf], 0, 0, 0);
            }
        }
        __builtin_amdgcn_s_setprio(0);
        int col = c * 16 + rlo;
        float bb = b1[col];
        #pragma unroll
        for (int rf = 0; rf < 4; ++rf) {
            #pragma unroll
            for (int r = 0; r < 4; ++r) {
                float v = fmaxf(aH[rf][r] + aL[rf][r] * (1.0f / 2048.0f) + bb, 0.f);
                Hs[(rf * 16 + quad * 4 + r) * HSTR2 + col] = f2h(v);
            }
        }
    }
    __syncthreads();   // barrier 1: H complete before GEMM2 reads

    // GEMM2: 2-chain f16 (A2 fragments straight from LDS, exact f16)
    f32x4 aH2[2][4], aL2[2][4];
    #pragma unroll
    for (int cc = 0; cc < 2; ++cc)
        #pragma unroll
        for (int rf = 0; rf < 4; ++rf) {
            aH2[cc][rf] = (f32x4){0.f, 0.f, 0.f, 0.f};
            aL2[cc][rf] = (f32x4){0.f, 0.f, 0.f, 0.f};
        }

    #pragma unroll
    for (int kc = 0; kc < 4; ++kc) {
        f16x8 a2[4];
        #pragma unroll
        for (int rf = 0; rf < 4; ++rf) {
            a2[rf] = as_f16x8(*(const u16x8*)&Hs[(rf * 16 + rlo) * HSTR2 + kc * 32 + quad * 8]);
        }
        __builtin_amdgcn_s_setprio(1);
        #pragma unroll
        for (int cc = 0; cc < 2; ++cc) {
            int c = 2 * wave + cc;
            f16x8 wh = W2h[(c * 4 + kc) * 64 + lane];
            f16x8 wl = W2l[(c * 4 + kc) * 64 + lane];
            #pragma unroll
            for (int rf = 0; rf < 4; ++rf) {
                aH2[cc][rf] = __builtin_amdgcn_mfma_f32_16x16x32_f16(a2[rf], wh, aH2[cc][rf], 0, 0, 0);
                aL2[cc][rf] = __builtin_amdgcn_mfma_f32_16x16x32_f16(a2[rf], wl, aL2[cc][rf], 0, 0, 0);
            }
        }
        __builtin_amdgcn_s_setprio(0);
    }
    // NO barrier here: epilogue-2 writes Ho (separate buffer), so GEMM2's
    // Hs reads have no WAR hazard.

    // epilogue 2: relu(acc + b2) -> fp16 in Ho, fused stats (fp32 pre-round)
    #pragma unroll
    for (int cc = 0; cc < 2; ++cc) {
        int c = 2 * wave + cc;
        int col = c * 16 + rlo;
        float bb = b2[col];
        float s = 0.f, s2 = 0.f;
        #pragma unroll
        for (int rf = 0; rf < 4; ++rf) {
            #pragma unroll
            for (int r = 0; r < 4; ++r) {
                float v = fmaxf(aH2[cc][rf][r] + aL2[cc][rf][r] * (1.0f / 2048.0f) + bb, 0.f);
                Ho[(rf * 16 + quad * 4 + r) * HSTR2 + col] = f2h(v);
                if (STATS) {
                    float m = (blk0 + rf * 16 + quad * 4 + r < N_NODES) ? v : 0.f;
                    s += m;
                    s2 += m * m;
                }
            }
        }
        if (STATS) {
            s  += __shfl_xor(s, 16, 64);
            s  += __shfl_xor(s, 32, 64);
            s2 += __shfl_xor(s2, 16, 64);
            s2 += __shfl_xor(s2, 32, 64);
            if (quad == 0) {
                atomicAdd(&stats[col], s);
                atomicAdd(&stats[D + col], s2);
            }
        }
    }
    __syncthreads();   // barrier 2: Ho complete before copy-out

    // coalesced fp16 copy-out: wave w writes rows [16w, 16w+16)
    #pragma unroll
    for (int it = 0; it < 4; ++it) {
        int r = wave * 16 + it * 4 + quad;
        int grow = blk0 + r;
        if (grow < N_NODES) {
            u16x8 vv = *(const u16x8*)&Ho[r * HSTR2 + rlo * 8];
            *(u16x8*)(Z + (size_t)grow * D + rlo * 8) = vv;
        }
    }
}

// ---------------------------------------------------------------------------
// Final: zn = BN(Z)*gamma+beta (fp32 out), p = PReLU(zn @ Wp + bp) (fp32 out)
// ---------------------------------------------------------------------------
#define PSTR 132   // floats
__global__ __launch_bounds__(256) void bn_proj(
    const ushort* __restrict__ Z, const float* __restrict__ stats,
    const float* __restrict__ gamma, const float* __restrict__ beta,
    const ushort* __restrict__ Wphi, const ushort* __restrict__ Wplo,
    const float* __restrict__ bp, const float* __restrict__ prelu_a,
    float* __restrict__ zn_out, float* __restrict__ p_out) {
    __shared__ float sc_s[D];
    __shared__ float sh_s[D];
    __shared__ float Ps[4][16 * PSTR];
    int tid = threadIdx.x;
    int lane = tid & 63;
    int wave = tid >> 6;
    int rlo = lane & 15;
    int quad = lane >> 4;

    if (tid < D) {
        float m = stats[tid] * (1.0f / N_NODES);
        float v = stats[D + tid] * (1.0f / N_NODES) - m * m;
        float rs = rsqrtf(v + BN_EPS);
        float sc = rs * gamma[tid];
        sc_s[tid] = sc;
        sh_s[tid] = beta[tid] - m * sc;
    }
    __syncthreads();

    int row0 = blockIdx.x * 64 + wave * 16;
    int arow = row0 + rlo;
    int ar = (arow < N_NODES) ? arow : (N_NODES - 1);

    const bf16x8* Wh = (const bf16x8*)Wphi;
    const bf16x8* Wl = (const bf16x8*)Wplo;

    // load Z frags, apply BN -> zn (fp32 store + split-bf16 a-frags)
    bf16x8 ahi[4], alo[4];
    #pragma unroll
    for (int kc = 0; kc < 4; ++kc) {
        u16x8 raw = *(const u16x8*)(Z + (size_t)ar * D + kc * 32 + quad * 8);
        float zn[8];
        #pragma unroll
        for (int j = 0; j < 8; ++j) {
            int k = kc * 32 + quad * 8 + j;
            zn[j] = sc_s[k] * h2f(raw[j]) + sh_s[k];
            unsigned short h = f2bf(zn[j]);
            ahi[kc][j] = (short)h;
            alo[kc][j] = (short)f2bf(zn[j] - bf2f(h));
        }
        if (arow < N_NODES) {
            float* dst = zn_out + (size_t)arow * D + kc * 32 + quad * 8;
            *(float4*)dst = make_float4(zn[0], zn[1], zn[2], zn[3]);
            *(float4*)(dst + 4) = make_float4(zn[4], zn[5], zn[6], zn[7]);
        }
    }

    f32x4 acc[8];
    #pragma unroll
    for (int c = 0; c < 8; ++c) acc[c] = (f32x4){0.f, 0.f, 0.f, 0.f};
    #pragma unroll
    for (int c = 0; c < 8; ++c) {
        #pragma unroll
        for (int kc = 0; kc < 4; ++kc) {
            bf16x8 wh = Wh[(c * 4 + kc) * 64 + lane];
            bf16x8 wl = Wl[(c * 4 + kc) * 64 + lane];
            acc[c] = __builtin_amdgcn_mfma_f32_16x16x32_bf16(alo[kc], wh, acc[c], 0, 0, 0);
            acc[c] = __builtin_amdgcn_mfma_f32_16x16x32_bf16(ahi[kc], wl, acc[c], 0, 0, 0);
            acc[c] = __builtin_amdgcn_mfma_f32_16x16x32_bf16(ahi[kc], wh, acc[c], 0, 0, 0);
        }
    }

    float aP = prelu_a[0];
    #pragma unroll
    for (int c = 0; c < 8; ++c) {
        int col = c * 16 + rlo;
        float bb = bp[col];
        #pragma unroll
        for (int r = 0; r < 4; ++r) {
            float v = acc[c][r] + bb;
            v = (v >= 0.f) ? v : aP * v;
            Ps[wave][(quad * 4 + r) * PSTR + col] = v;
        }
    }
    __syncthreads();
    #pragma unroll
    for (int p2 = 0; p2 < 8; ++p2) {
        int r = p2 * 2 + (lane >> 5);
        int grow = row0 + r;
        if (grow < N_NODES) {
            *(float4*)(p_out + (size_t)grow * D + (lane & 31) * 4) =
                *(const float4*)&Ps[wave][r * PSTR + (lane & 31) * 4];
        }
    }
}

// ---------------------------------------------------------------------------
extern "C" void kernel_launch(void* const* d_in, const int* in_sizes, int n_in,
                              void* d_out, int out_size, void* d_ws, size_t ws_size,
                              hipStream_t stream) {
    (void)in_sizes; (void)n_in; (void)out_size; (void)ws_size;
    const float* x     = (const float*)d_in[0];
    const float* ew    = (const float*)d_in[1];
    const float* W1s   = (const float*)d_in[2];
    const float* b1s   = (const float*)d_in[3];
    const float* W2s   = (const float*)d_in[4];
    const float* b2s   = (const float*)d_in[5];
    const float* eps   = (const float*)d_in[6];
    const float* gamma = (const float*)d_in[7];
    const float* beta  = (const float*)d_in[8];
    const float* Wp    = (const float*)d_in[9];
    const float* bp    = (const float*)d_in[10];
    const float* pa    = (const float*)d_in[11];
    const int*   ei    = (const int*)d_in[12];
    const int* srcp = ei;
    const int* dstp = ei + N_EDGES;

    // workspace layout (bytes):
    char* wsb = (char*)d_ws;
    float*  stats  = (float*)wsb;                 wsb += 1024;           // 256 f
    int*    offs   = (int*)wsb;                   wsb += 200016;         // 50004 i
    int*    bcur   = (int*)wsb;                   // 256 i
    int*    gbcnt  = bcur + 256;                  // 256 i
    int*    bstart = bcur + 512;                  wsb += 200016;         // 257 i
    uint2*  pay    = (uint2*)wsb;                 wsb += 6400000;        // 800000 uint2
    ushort* Wpk    = (ushort*)wsb;                wsb += 14 * 16384 * 2; // split weights
    ushort* Xh     = (ushort*)wsb;                wsb += (size_t)ND * 2; // x in fp16
    ushort* Ah     = (ushort*)wsb;                wsb += (size_t)ND * 2; // gather out fp16
    ushort* Zh     = (ushort*)wsb;                wsb += (size_t)ND * 2; // layer out fp16

    float* out_zn = (float*)d_out;
    float* out_p  = out_zn + ND;

    hipMemsetAsync(stats, 0, 256 * sizeof(float), stream);
    hipMemsetAsync(gbcnt, 0, NB * sizeof(int), stream);

    convert_x<<<(ND / 4 + 255) / 256, 256, 0, stream>>>(x, Xh);
    pack_w_split<<<(7 * 16384 + 255) / 256, 256, 0, stream>>>(W1s, W2s, Wp, Wpk);

    bhist_kernel<<<(N_EDGES + 2047) / 2048, 256, 0, stream>>>(dstp, gbcnt);
    bscan_kernel<<<1, 256, 0, stream>>>(gbcnt, bstart, bcur);
    bucket_scatter<<<(N_EDGES + 2047) / 2048, 256, 0, stream>>>(srcp, dstp, ew, bcur, pay);
    bucket_sort<<<NB, 256, 0, stream>>>(bstart, offs, pay);

    int mgrid = (N_NODES + 63) / 64;
    const ushort* zin = Xh;
    for (int l = 0; l < 3; ++l) {
        gather_agg_f16<<<(N_NODES * 32 + 255) / 256, 256, 0, stream>>>(zin, offs, pay, eps, l, Ah);
        if (l < 2) {
            mlp_fused<false><<<mgrid, 256, 0, stream>>>(Ah,
                Wpk + (size_t)(2 * l) * 16384,       Wpk + (size_t)(2 * l + 1) * 16384, b1s + (size_t)l * D,
                Wpk + (size_t)(2 * (3 + l)) * 16384, Wpk + (size_t)(2 * (3 + l) + 1) * 16384, b2s + (size_t)l * D,
                Zh, stats);
        } else {
            mlp_fused<true><<<mgrid, 256, 0, stream>>>(Ah,
                Wpk + (size_t)(2 * l) * 16384,       Wpk + (size_t)(2 * l + 1) * 16384, b1s + (size_t)l * D,
                Wpk + (size_t)(2 * (3 + l)) * 16384, Wpk + (size_t)(2 * (3 + l) + 1) * 16384, b2s + (size_t)l * D,
                Zh, stats);
        }
        zin = Zh;
    }
    bn_proj<<<mgrid, 256, 0, stream>>>(Zh, stats, gamma, beta,
        Wpk + (size_t)12 * 16384, Wpk + (size_t)13 * 16384, bp, pa, out_zn, out_p);
}

// Round 12
// 355.970 us; speedup vs baseline: 1.0683x; 1.0376x over previous
//
#include <hip/hip_runtime.h>
#include <hip/hip_fp16.h>

#define N_NODES 50000
#define N_EDGES 800000
#define D 128
#define ND (N_NODES * D)
#define BN_EPS 1e-5f

// bucketed CSR build
#define NB 256      // coarse buckets
#define NPB 196     // nodes per bucket (256*196 = 50176 >= 50000)
#define BCAP 4096   // max edges per bucket (mean 3136, sigma 56 -> 17 sigma headroom)

typedef short bf16x8 __attribute__((ext_vector_type(8)));
typedef _Float16 f16x8 __attribute__((ext_vector_type(8)));
typedef float f32x4 __attribute__((ext_vector_type(4)));
typedef unsigned short u16x8 __attribute__((ext_vector_type(8)));

__device__ inline unsigned short f2bf(float f) {
    unsigned int u = __float_as_uint(f);
    u += 0x7FFF + ((u >> 16) & 1);
    return (unsigned short)(u >> 16);
}
__device__ inline float bf2f(unsigned short h) {
    return __uint_as_float(((unsigned int)h) << 16);
}
__device__ inline unsigned short f2h(float f) {
    return __half_as_ushort(__float2half(f));
}
__device__ inline float h2f(unsigned short u) {
    return __half2float(__ushort_as_half(u));
}
__device__ inline f16x8 as_f16x8(u16x8 v) {
    union { u16x8 u; f16x8 f; } x; x.u = v; return x.f;
}
__device__ inline bf16x8 as_bf16x8(u16x8 v) {
    union { u16x8 u; bf16x8 f; } x; x.u = v; return x.f;
}

// ---------------------------------------------------------------------------
// Convert x (fp32) -> fp16
// ---------------------------------------------------------------------------
__global__ void convert_x(const float* __restrict__ x, ushort* __restrict__ xh) {
    int i = (blockIdx.x * blockDim.x + threadIdx.x) * 4;
    if (i < ND) {
        float4 v = *(const float4*)(x + i);
        *(ushort4*)(xh + i) = make_ushort4(f2h(v.x), f2h(v.y), f2h(v.z), f2h(v.w));
    }
}

// ---------------------------------------------------------------------------
// Pack 7 weight matrices [128x128] fp32 into MFMA B-fragment pairs.
// m < 6  (W1, W2 layers): fp16 hi + fp16((v-hi)*2048) lo -> 2-chain f16 MFMA
// m == 6 (Wp):            split-bf16 hi/lo -> 3-term bf16 MFMA (bn_proj)
// ---------------------------------------------------------------------------
__global__ void pack_w_split(const float* __restrict__ W1s, const float* __restrict__ W2s,
                             const float* __restrict__ Wp, ushort* __restrict__ out) {
    int idx = blockIdx.x * blockDim.x + threadIdx.x;
    if (idx >= 7 * 16384) return;
    int m = idx >> 14;
    int p = idx & 16383;
    int c = p >> 11;
    int kc = (p >> 9) & 3;
    int lane = (p >> 3) & 63;
    int j = p & 7;
    int k = kc * 32 + (lane >> 4) * 8 + j;
    int col = c * 16 + (lane & 15);
    const float* src = (m < 3) ? (W1s + (size_t)m * 16384)
                     : (m < 6) ? (W2s + (size_t)(m - 3) * 16384)
                               : Wp;
    float v = src[k * 128 + col];
    if (m < 6) {
        unsigned short hi = f2h(v);
        float r = (v - h2f(hi)) * 2048.0f;
        out[(size_t)(2 * m) * 16384 + p] = hi;
        out[(size_t)(2 * m + 1) * 16384 + p] = f2h(r);
    } else {
        unsigned short hi = f2bf(v);
        float r = v - bf2f(hi);
        out[(size_t)(2 * m) * 16384 + p] = hi;
        out[(size_t)(2 * m + 1) * 16384 + p] = f2bf(r);
    }
}

// ---------------------------------------------------------------------------
// CSR build step 1: per-block LDS histogram of coarse buckets -> global counts
// ---------------------------------------------------------------------------
__global__ __launch_bounds__(256) void bhist_kernel(const int* __restrict__ dst,
                                                    int* __restrict__ gbcnt) {
    __shared__ int cnt[NB];
    int tid = threadIdx.x;
    cnt[tid] = 0;
    __syncthreads();
    int base = blockIdx.x * 2048;
    #pragma unroll
    for (int k = 0; k < 8; ++k) {
        int e = base + k * 256 + tid;
        if (e < N_EDGES) atomicAdd(&cnt[dst[e] / NPB], 1);
    }
    __syncthreads();
    int c = cnt[tid];
    if (c > 0) atomicAdd(&gbcnt[tid], c);
}

// ---------------------------------------------------------------------------
// CSR build step 2: exclusive scan of the 256 bucket counts (one tiny block).
// ---------------------------------------------------------------------------
__global__ __launch_bounds__(256) void bscan_kernel(const int* __restrict__ gbcnt,
                                                    int* __restrict__ bstart,
                                                    int* __restrict__ bcur) {
    __shared__ int s[NB];
    int tid = threadIdx.x;
    int v = gbcnt[tid];
    s[tid] = v;
    __syncthreads();
    for (int d = 1; d < NB; d <<= 1) {
        int t = (tid >= d) ? s[tid - d] : 0;
        __syncthreads();
        s[tid] += t;
        __syncthreads();
    }
    int incl = s[tid];
    bstart[tid] = incl - v;
    bcur[tid] = incl - v;
    if (tid == NB - 1) bstart[NB] = incl;
}

// ---------------------------------------------------------------------------
// CSR build step 3a: coarse bucket scatter.
// ---------------------------------------------------------------------------
__global__ __launch_bounds__(256) void bucket_scatter(
    const int* __restrict__ src, const int* __restrict__ dst,
    const float* __restrict__ ew, int* __restrict__ bcur,
    uint2* __restrict__ pay) {
    __shared__ int cnt[NB];
    __shared__ int cur[NB];
    int tid = threadIdx.x;
    for (int i = tid; i < NB; i += 256) cnt[i] = 0;
    __syncthreads();
    int base = blockIdx.x * 2048;
    int s[8], d[8], b[8];
    float w[8];
    #pragma unroll
    for (int k = 0; k < 8; ++k) {
        int e = base + k * 256 + tid;
        bool v = e < N_EDGES;
        d[k] = v ? dst[e] : 0;
        s[k] = v ? src[e] : 0;
        w[k] = v ? ew[e] : 0.f;
        b[k] = d[k] / NPB;                 // constant div -> magic mul
        if (v) atomicAdd(&cnt[b[k]], 1);
    }
    __syncthreads();
    for (int i = tid; i < NB; i += 256) {
        int c = cnt[i];
        cur[i] = (c > 0) ? atomicAdd(&bcur[i], c) : 0;
    }
    __syncthreads();
    #pragma unroll
    for (int k = 0; k < 8; ++k) {
        int e = base + k * 256 + tid;
        if (e < N_EDGES) {
            int bk = b[k];
            int p = atomicAdd(&cur[bk], 1);
            unsigned dloc = (unsigned)(d[k] - bk * NPB);
            pay[p] = make_uint2((unsigned)s[k] | (dloc << 17), __float_as_uint(w[k]));
        }
    }
}

// ---------------------------------------------------------------------------
// CSR build step 3b: per-bucket exact sort, in place; also writes offs.
// ---------------------------------------------------------------------------
__global__ __launch_bounds__(256) void bucket_sort(const int* __restrict__ bstart,
                                                   int* __restrict__ offs,
                                                   uint2* __restrict__ pay) {
    __shared__ uint2 lp[BCAP];
    __shared__ int lcnt[NB];
    __shared__ int cur[NPB];
    int b = blockIdx.x;
    int tid = threadIdx.x;
    int n0 = b * NPB;
    int n1 = min(n0 + NPB, N_NODES);
    int nn = n1 - n0;
    int r0 = bstart[b];
    int r1 = bstart[b + 1];
    int cnt = r1 - r0;
    lcnt[tid] = 0;
    __syncthreads();
    for (int i = tid; i < cnt; i += 256) {
        uint2 e = pay[r0 + i];
        if (i < BCAP) lp[i] = e;
        atomicAdd(&lcnt[e.x >> 17], 1);
    }
    __syncthreads();
    int v = lcnt[tid];
    for (int d = 1; d < NB; d <<= 1) {
        int t = (tid >= d) ? lcnt[tid - d] : 0;
        __syncthreads();
        lcnt[tid] += t;
        __syncthreads();
    }
    int excl = lcnt[tid] - v;
    if (tid < nn) {
        offs[n0 + tid] = r0 + excl;
        cur[tid] = excl;
    }
    if (tid == 0) offs[n1] = r1;
    __syncthreads();
    for (int i = tid; i < cnt; i += 256) {
        if (i < BCAP) {
            uint2 e = lp[i];
            int p = atomicAdd(&cur[e.x >> 17], 1);
            if (p < BCAP) pay[r0 + p] = make_uint2(e.x & 0x1FFFFu, e.y);
        }
    }
}

// ---------------------------------------------------------------------------
// Gather-aggregate + GIN combine (fp16 in, fp32 accumulate, fp16 out).
// 32 lanes/node (max TLP), edge loop unrolled x8 for memory-level parallelism.
// ---------------------------------------------------------------------------
__global__ void gather_agg_f16(const ushort* __restrict__ z, const int* __restrict__ offs,
                               const uint2* __restrict__ pay,
                               const float* __restrict__ epsp, int layer,
                               ushort* __restrict__ A) {
    int tid = blockIdx.x * blockDim.x + threadIdx.x;
    int n = tid >> 5;
    if (n >= N_NODES) return;
    int f = (tid & 31) << 2;
    float epsv = 1.0f + epsp[layer];
    int beg = offs[n], end = offs[n + 1];
    ushort4 zi = *(const ushort4*)(z + (size_t)n * D + f);
    float ax = epsv * h2f(zi.x), ay = epsv * h2f(zi.y);
    float az = epsv * h2f(zi.z), aw = epsv * h2f(zi.w);
    int j = beg;
    for (; j + 8 <= end; j += 8) {
        uint2 e[8];
        #pragma unroll
        for (int k = 0; k < 8; ++k) e[k] = pay[j + k];
        ushort4 v[8];
        #pragma unroll
        for (int k = 0; k < 8; ++k) v[k] = *(const ushort4*)(z + (size_t)e[k].x * D + f);
        #pragma unroll
        for (int k = 0; k < 8; ++k) {
            float w = __uint_as_float(e[k].y);
            ax += h2f(v[k].x) * w; ay += h2f(v[k].y) * w;
            az += h2f(v[k].z) * w; aw += h2f(v[k].w) * w;
        }
    }
    for (; j + 4 <= end; j += 4) {
        uint2 e0 = pay[j];
        uint2 e1 = pay[j + 1];
        uint2 e2 = pay[j + 2];
        uint2 e3 = pay[j + 3];
        ushort4 v0 = *(const ushort4*)(z + (size_t)e0.x * D + f);
        ushort4 v1 = *(const ushort4*)(z + (size_t)e1.x * D + f);
        ushort4 v2 = *(const ushort4*)(z + (size_t)e2.x * D + f);
        ushort4 v3 = *(const ushort4*)(z + (size_t)e3.x * D + f);
        float w0 = __uint_as_float(e0.y);
        float w1 = __uint_as_float(e1.y);
        float w2 = __uint_as_float(e2.y);
        float w3 = __uint_as_float(e3.y);
        ax += h2f(v0.x) * w0 + h2f(v1.x) * w1 + h2f(v2.x) * w2 + h2f(v3.x) * w3;
        ay += h2f(v0.y) * w0 + h2f(v1.y) * w1 + h2f(v2.y) * w2 + h2f(v3.y) * w3;
        az += h2f(v0.z) * w0 + h2f(v1.z) * w1 + h2f(v2.z) * w2 + h2f(v3.z) * w3;
        aw += h2f(v0.w) * w0 + h2f(v1.w) * w1 + h2f(v2.w) * w2 + h2f(v3.w) * w3;
    }
    for (; j < end; ++j) {
        uint2 e0 = pay[j];
        ushort4 v0 = *(const ushort4*)(z + (size_t)e0.x * D + f);
        float w0 = __uint_as_float(e0.y);
        ax += h2f(v0.x) * w0; ay += h2f(v0.y) * w0;
        az += h2f(v0.z) * w0; aw += h2f(v0.w) * w0;
    }
    *(ushort4*)(A + (size_t)n * D + f) = make_ushort4(f2h(ax), f2h(ay), f2h(az), f2h(aw));
}

// ---------------------------------------------------------------------------
// Fused GIN MLP — c-split, 64-row blocks (round-9 structure) + W2 register
// prefetch: all 16 W2 fragments are loaded at kernel entry, so their L2
// latency hides under GEMM1 compute and GEMM2 after barrier 1 is pure
// LDS-read + MFMA (T14 issue-early/consume-late). VGPR ~144 still allows
// 3 waves/SIMD = the grid cap (3 blocks/CU x 4 waves) -> no occupancy loss.
// GEMM1 & GEMM2: 2-chain f16 MFMA (W = f16 hi + 2048-scaled f16 lo).
// H in LDS as plain fp16 (17.4 KB/block, 3 barriers as in round 9).
// ---------------------------------------------------------------------------
#define HSTR2 136   // ushorts: 128 + 8 pad -> 272B row stride
template<bool STATS>
__global__ __launch_bounds__(256) void mlp_fused(
    const ushort* __restrict__ A,
    const ushort* __restrict__ W1hi, const ushort* __restrict__ W1lo,
    const float* __restrict__ b1,
    const ushort* __restrict__ W2hi, const ushort* __restrict__ W2lo,
    const float* __restrict__ b2, ushort* __restrict__ Z,
    float* __restrict__ stats) {
    __shared__ ushort Hs[64 * HSTR2];
    int tid = threadIdx.x;
    int lane = tid & 63;
    int wave = tid >> 6;
    int rlo = lane & 15;
    int quad = lane >> 4;
    int blk0 = blockIdx.x * 64;

    const f16x8* W1h = (const f16x8*)W1hi;
    const f16x8* W1l = (const f16x8*)W1lo;
    const f16x8* W2hp = (const f16x8*)W2hi;
    const f16x8* W2lp = (const f16x8*)W2lo;

    // A fragments for all 4 row-frags (all waves load the same tile -> L1)
    f16x8 af[4][4];
    #pragma unroll
    for (int rf = 0; rf < 4; ++rf) {
        int arow = blk0 + rf * 16 + rlo;
        int ar = (arow < N_NODES) ? arow : (N_NODES - 1);
        #pragma unroll
        for (int kc = 0; kc < 4; ++kc) {
            u16x8 raw = *(const u16x8*)(A + (size_t)ar * D + kc * 32 + quad * 8);
            af[rf][kc] = as_f16x8(raw);
        }
    }

    // W2 prefetch: issue ALL GEMM2 weight loads now (no data dependency);
    // latency hides under GEMM1. 16 frags x 4 VGPR = 64 VGPR.
    f16x8 w2h[2][4], w2l[2][4];
    #pragma unroll
    for (int cc = 0; cc < 2; ++cc) {
        int c = 2 * wave + cc;
        #pragma unroll
        for (int kc = 0; kc < 4; ++kc) {
            w2h[cc][kc] = W2hp[(c * 4 + kc) * 64 + lane];
            w2l[cc][kc] = W2lp[(c * 4 + kc) * 64 + lane];
        }
    }

    // GEMM1: wave computes its 2 column-groups for all 4 row-frags;
    // epilogue-1 stores H as plain f16 to LDS.
    #pragma unroll
    for (int cc = 0; cc < 2; ++cc) {
        int c = 2 * wave + cc;
        f32x4 aH[4], aL[4];
        #pragma unroll
        for (int rf = 0; rf < 4; ++rf) {
            aH[rf] = (f32x4){0.f, 0.f, 0.f, 0.f};
            aL[rf] = (f32x4){0.f, 0.f, 0.f, 0.f};
        }
        #pragma unroll
        for (int kc = 0; kc < 4; ++kc) {
            f16x8 wh = W1h[(c * 4 + kc) * 64 + lane];
            f16x8 wl = W1l[(c * 4 + kc) * 64 + lane];
            #pragma unroll
            for (int rf = 0; rf < 4; ++rf) {
                aH[rf] = __builtin_amdgcn_mfma_f32_16x16x32_f16(af[rf][kc], wh, aH[rf], 0, 0, 0);
                aL[rf] = __builtin_amdgcn_mfma_f32_16x16x32_f16(af[rf][kc], wl, aL[rf], 0, 0, 0);
            }
        }
        int col = c * 16 + rlo;
        float bb = b1[col];
        #pragma unroll
        for (int rf = 0; rf < 4; ++rf) {
            #pragma unroll
            for (int r = 0; r < 4; ++r) {
                float v = fmaxf(aH[rf][r] + aL[rf][r] * (1.0f / 2048.0f) + bb, 0.f);
                Hs[(rf * 16 + quad * 4 + r) * HSTR2 + col] = f2h(v);
            }
        }
    }
    __syncthreads();

    // GEMM2: pure LDS-read + MFMA (weights already in registers)
    f32x4 aH2[2][4], aL2[2][4];
    #pragma unroll
    for (int cc = 0; cc < 2; ++cc)
        #pragma unroll
        for (int rf = 0; rf < 4; ++rf) {
            aH2[cc][rf] = (f32x4){0.f, 0.f, 0.f, 0.f};
            aL2[cc][rf] = (f32x4){0.f, 0.f, 0.f, 0.f};
        }

    #pragma unroll
    for (int kc = 0; kc < 4; ++kc) {
        f16x8 a2[4];
        #pragma unroll
        for (int rf = 0; rf < 4; ++rf) {
            a2[rf] = as_f16x8(*(const u16x8*)&Hs[(rf * 16 + rlo) * HSTR2 + kc * 32 + quad * 8]);
        }
        #pragma unroll
        for (int cc = 0; cc < 2; ++cc) {
            #pragma unroll
            for (int rf = 0; rf < 4; ++rf) {
                aH2[cc][rf] = __builtin_amdgcn_mfma_f32_16x16x32_f16(a2[rf], w2h[cc][kc], aH2[cc][rf], 0, 0, 0);
                aL2[cc][rf] = __builtin_amdgcn_mfma_f32_16x16x32_f16(a2[rf], w2l[cc][kc], aL2[cc][rf], 0, 0, 0);
            }
        }
    }
    __syncthreads();   // all LDS reads done before epilogue-2 overwrites

    // epilogue 2: relu(acc + b2) -> fp16 in Hs, fused stats (fp32 pre-round)
    #pragma unroll
    for (int cc = 0; cc < 2; ++cc) {
        int c = 2 * wave + cc;
        int col = c * 16 + rlo;
        float bb = b2[col];
        float s = 0.f, s2 = 0.f;
        #pragma unroll
        for (int rf = 0; rf < 4; ++rf) {
            #pragma unroll
            for (int r = 0; r < 4; ++r) {
                float v = fmaxf(aH2[cc][rf][r] + aL2[cc][rf][r] * (1.0f / 2048.0f) + bb, 0.f);
                Hs[(rf * 16 + quad * 4 + r) * HSTR2 + col] = f2h(v);
                if (STATS) {
                    float m = (blk0 + rf * 16 + quad * 4 + r < N_NODES) ? v : 0.f;
                    s += m;
                    s2 += m * m;
                }
            }
        }
        if (STATS) {
            s  += __shfl_xor(s, 16, 64);
            s  += __shfl_xor(s, 32, 64);
            s2 += __shfl_xor(s2, 16, 64);
            s2 += __shfl_xor(s2, 32, 64);
            if (quad == 0) {
                atomicAdd(&stats[col], s);
                atomicAdd(&stats[D + col], s2);
            }
        }
    }
    __syncthreads();

    // coalesced fp16 copy-out: wave w writes rows [16w, 16w+16)
    #pragma unroll
    for (int it = 0; it < 4; ++it) {
        int r = wave * 16 + it * 4 + quad;
        int grow = blk0 + r;
        if (grow < N_NODES) {
            u16x8 vv = *(const u16x8*)&Hs[r * HSTR2 + rlo * 8];
            *(u16x8*)(Z + (size_t)grow * D + rlo * 8) = vv;
        }
    }
}

// ---------------------------------------------------------------------------
// Final: zn = BN(Z)*gamma+beta (fp32 out), p = PReLU(zn @ Wp + bp) (fp32 out)
// ---------------------------------------------------------------------------
#define PSTR 132   // floats
__global__ __launch_bounds__(256) void bn_proj(
    const ushort* __restrict__ Z, const float* __restrict__ stats,
    const float* __restrict__ gamma, const float* __restrict__ beta,
    const ushort* __restrict__ Wphi, const ushort* __restrict__ Wplo,
    const float* __restrict__ bp, const float* __restrict__ prelu_a,
    float* __restrict__ zn_out, float* __restrict__ p_out) {
    __shared__ float sc_s[D];
    __shared__ float sh_s[D];
    __shared__ float Ps[4][16 * PSTR];
    int tid = threadIdx.x;
    int lane = tid & 63;
    int wave = tid >> 6;
    int rlo = lane & 15;
    int quad = lane >> 4;

    if (tid < D) {
        float m = stats[tid] * (1.0f / N_NODES);
        float v = stats[D + tid] * (1.0f / N_NODES) - m * m;
        float rs = rsqrtf(v + BN_EPS);
        float sc = rs * gamma[tid];
        sc_s[tid] = sc;
        sh_s[tid] = beta[tid] - m * sc;
    }
    __syncthreads();

    int row0 = blockIdx.x * 64 + wave * 16;
    int arow = row0 + rlo;
    int ar = (arow < N_NODES) ? arow : (N_NODES - 1);

    const bf16x8* Wh = (const bf16x8*)Wphi;
    const bf16x8* Wl = (const bf16x8*)Wplo;

    // load Z frags, apply BN -> zn (fp32 store + split-bf16 a-frags)
    bf16x8 ahi[4], alo[4];
    #pragma unroll
    for (int kc = 0; kc < 4; ++kc) {
        u16x8 raw = *(const u16x8*)(Z + (size_t)ar * D + kc * 32 + quad * 8);
        float zn[8];
        #pragma unroll
        for (int j = 0; j < 8; ++j) {
            int k = kc * 32 + quad * 8 + j;
            zn[j] = sc_s[k] * h2f(raw[j]) + sh_s[k];
            unsigned short h = f2bf(zn[j]);
            ahi[kc][j] = (short)h;
            alo[kc][j] = (short)f2bf(zn[j] - bf2f(h));
        }
        if (arow < N_NODES) {
            float* dst = zn_out + (size_t)arow * D + kc * 32 + quad * 8;
            *(float4*)dst = make_float4(zn[0], zn[1], zn[2], zn[3]);
            *(float4*)(dst + 4) = make_float4(zn[4], zn[5], zn[6], zn[7]);
        }
    }

    f32x4 acc[8];
    #pragma unroll
    for (int c = 0; c < 8; ++c) acc[c] = (f32x4){0.f, 0.f, 0.f, 0.f};
    #pragma unroll
    for (int c = 0; c < 8; ++c) {
        #pragma unroll
        for (int kc = 0; kc < 4; ++kc) {
            bf16x8 wh = Wh[(c * 4 + kc) * 64 + lane];
            bf16x8 wl = Wl[(c * 4 + kc) * 64 + lane];
            acc[c] = __builtin_amdgcn_mfma_f32_16x16x32_bf16(alo[kc], wh, acc[c], 0, 0, 0);
            acc[c] = __builtin_amdgcn_mfma_f32_16x16x32_bf16(ahi[kc], wl, acc[c], 0, 0, 0);
            acc[c] = __builtin_amdgcn_mfma_f32_16x16x32_bf16(ahi[kc], wh, acc[c], 0, 0, 0);
        }
    }

    float aP = prelu_a[0];
    #pragma unroll
    for (int c = 0; c < 8; ++c) {
        int col = c * 16 + rlo;
        float bb = bp[col];
        #pragma unroll
        for (int r = 0; r < 4; ++r) {
            float v = acc[c][r] + bb;
            v = (v >= 0.f) ? v : aP * v;
            Ps[wave][(quad * 4 + r) * PSTR + col] = v;
        }
    }
    __syncthreads();
    #pragma unroll
    for (int p2 = 0; p2 < 8; ++p2) {
        int r = p2 * 2 + (lane >> 5);
        int grow = row0 + r;
        if (grow < N_NODES) {
            *(float4*)(p_out + (size_t)grow * D + (lane & 31) * 4) =
                *(const float4*)&Ps[wave][r * PSTR + (lane & 31) * 4];
        }
    }
}

// ---------------------------------------------------------------------------
extern "C" void kernel_launch(void* const* d_in, const int* in_sizes, int n_in,
                              void* d_out, int out_size, void* d_ws, size_t ws_size,
                              hipStream_t stream) {
    (void)in_sizes; (void)n_in; (void)out_size; (void)ws_size;
    const float* x     = (const float*)d_in[0];
    const float* ew    = (const float*)d_in[1];
    const float* W1s   = (const float*)d_in[2];
    const float* b1s   = (const float*)d_in[3];
    const float* W2s   = (const float*)d_in[4];
    const float* b2s   = (const float*)d_in[5];
    const float* eps   = (const float*)d_in[6];
    const float* gamma = (const float*)d_in[7];
    const float* beta  = (const float*)d_in[8];
    const float* Wp    = (const float*)d_in[9];
    const float* bp    = (const float*)d_in[10];
    const float* pa    = (const float*)d_in[11];
    const int*   ei    = (const int*)d_in[12];
    const int* srcp = ei;
    const int* dstp = ei + N_EDGES;

    // workspace layout (bytes):
    char* wsb = (char*)d_ws;
    float*  stats  = (float*)wsb;                 wsb += 1024;           // 256 f
    int*    offs   = (int*)wsb;                   wsb += 200016;         // 50004 i
    int*    bcur   = (int*)wsb;                   // 256 i
    int*    gbcnt  = bcur + 256;                  // 256 i
    int*    bstart = bcur + 512;                  wsb += 200016;         // 257 i
    uint2*  pay    = (uint2*)wsb;                 wsb += 6400000;        // 800000 uint2
    ushort* Wpk    = (ushort*)wsb;                wsb += 14 * 16384 * 2; // split weights
    ushort* Xh     = (ushort*)wsb;                wsb += (size_t)ND * 2; // x in fp16
    ushort* Ah     = (ushort*)wsb;                wsb += (size_t)ND * 2; // gather out fp16
    ushort* Zh     = (ushort*)wsb;                wsb += (size_t)ND * 2; // layer out fp16

    float* out_zn = (float*)d_out;
    float* out_p  = out_zn + ND;

    hipMemsetAsync(stats, 0, 256 * sizeof(float), stream);
    hipMemsetAsync(gbcnt, 0, NB * sizeof(int), stream);

    convert_x<<<(ND / 4 + 255) / 256, 256, 0, stream>>>(x, Xh);
    pack_w_split<<<(7 * 16384 + 255) / 256, 256, 0, stream>>>(W1s, W2s, Wp, Wpk);

    bhist_kernel<<<(N_EDGES + 2047) / 2048, 256, 0, stream>>>(dstp, gbcnt);
    bscan_kernel<<<1, 256, 0, stream>>>(gbcnt, bstart, bcur);
    bucket_scatter<<<(N_EDGES + 2047) / 2048, 256, 0, stream>>>(srcp, dstp, ew, bcur, pay);
    bucket_sort<<<NB, 256, 0, stream>>>(bstart, offs, pay);

    int mgrid = (N_NODES + 63) / 64;
    const ushort* zin = Xh;
    for (int l = 0; l < 3; ++l) {
        gather_agg_f16<<<(N_NODES * 32 + 255) / 256, 256, 0, stream>>>(zin, offs, pay, eps, l, Ah);
        if (l < 2) {
            mlp_fused<false><<<mgrid, 256, 0, stream>>>(Ah,
                Wpk + (size_t)(2 * l) * 16384,       Wpk + (size_t)(2 * l + 1) * 16384, b1s + (size_t)l * D,
                Wpk + (size_t)(2 * (3 + l)) * 16384, Wpk + (size_t)(2 * (3 + l) + 1) * 16384, b2s + (size_t)l * D,
                Zh, stats);
        } else {
            mlp_fused<true><<<mgrid, 256, 0, stream>>>(Ah,
                Wpk + (size_t)(2 * l) * 16384,       Wpk + (size_t)(2 * l + 1) * 16384, b1s + (size_t)l * D,
                Wpk + (size_t)(2 * (3 + l)) * 16384, Wpk + (size_t)(2 * (3 + l) + 1) * 16384, b2s + (size_t)l * D,
                Zh, stats);
        }
        zin = Zh;
    }
    bn_proj<<<mgrid, 256, 0, stream>>>(Zh, stats, gamma, beta,
        Wpk + (size_t)12 * 16384, Wpk + (size_t)13 * 16384, bp, pa, out_zn, out_p);
}

// Round 14
// 353.286 us; speedup vs baseline: 1.0764x; 1.0076x over previous
//
#include <hip/hip_runtime.h>
#include <hip/hip_fp16.h>

#define N_NODES 50000
#define N_EDGES 800000
#define D 128
#define ND (N_NODES * D)
#define BN_EPS 1e-5f

// bucketed CSR build
#define NB 256      // coarse buckets
#define NPB 196     // nodes per bucket (256*196 = 50176 >= 50000)
#define BCAP 4096   // max edges per bucket (mean 3136, sigma 56 -> 17 sigma headroom)

// merged prologue block ranges
#define NB_CONV 6250   // ND/4/256
#define NB_PACK 448    // 7*16384/256
#define NB_HIST 391    // ceil(N_EDGES/2048)

typedef short bf16x8 __attribute__((ext_vector_type(8)));
typedef _Float16 f16x8 __attribute__((ext_vector_type(8)));
typedef float f32x4 __attribute__((ext_vector_type(4)));
typedef unsigned short u16x8 __attribute__((ext_vector_type(8)));

__device__ inline unsigned short f2bf(float f) {
    unsigned int u = __float_as_uint(f);
    u += 0x7FFF + ((u >> 16) & 1);
    return (unsigned short)(u >> 16);
}
__device__ inline float bf2f(unsigned short h) {
    return __uint_as_float(((unsigned int)h) << 16);
}
__device__ inline unsigned short f2h(float f) {
    return __half_as_ushort(__float2half(f));
}
__device__ inline float h2f(unsigned short u) {
    return __half2float(__ushort_as_half(u));
}
__device__ inline f16x8 as_f16x8(u16x8 v) {
    union { u16x8 u; f16x8 f; } x; x.u = v; return x.f;
}
__device__ inline bf16x8 as_bf16x8(u16x8 v) {
    union { u16x8 u; bf16x8 f; } x; x.u = v; return x.f;
}

// ---------------------------------------------------------------------------
// Merged prologue: [0,NB_CONV) convert x->fp16 | [..+NB_PACK) pack weights |
// [..+NB_HIST) coarse-bucket histogram. Independent jobs, one launch.
// ---------------------------------------------------------------------------
__global__ __launch_bounds__(256) void prologue(
    const float* __restrict__ x, ushort* __restrict__ xh,
    const float* __restrict__ W1s, const float* __restrict__ W2s,
    const float* __restrict__ Wp, ushort* __restrict__ wout,
    const int* __restrict__ dst, int* __restrict__ gbcnt) {
    __shared__ int cnt[NB];
    int b = blockIdx.x;
    int tid = threadIdx.x;
    if (b < NB_CONV) {
        int i = (b * 256 + tid) * 4;
        if (i < ND) {
            float4 v = *(const float4*)(x + i);
            *(ushort4*)(xh + i) = make_ushort4(f2h(v.x), f2h(v.y), f2h(v.z), f2h(v.w));
        }
    } else if (b < NB_CONV + NB_PACK) {
        int idx = (b - NB_CONV) * 256 + tid;
        int m = idx >> 14;
        int p = idx & 16383;
        int c = p >> 11;
        int kc = (p >> 9) & 3;
        int lane = (p >> 3) & 63;
        int j = p & 7;
        int k = kc * 32 + (lane >> 4) * 8 + j;
        int col = c * 16 + (lane & 15);
        const float* src = (m < 3) ? (W1s + (size_t)m * 16384)
                         : (m < 6) ? (W2s + (size_t)(m - 3) * 16384)
                                   : Wp;
        float v = src[k * 128 + col];
        if (m < 6) {
            unsigned short hi = f2h(v);
            float r = (v - h2f(hi)) * 2048.0f;
            wout[(size_t)(2 * m) * 16384 + p] = hi;
            wout[(size_t)(2 * m + 1) * 16384 + p] = f2h(r);
        } else {
            unsigned short hi = f2bf(v);
            float r = v - bf2f(hi);
            wout[(size_t)(2 * m) * 16384 + p] = hi;
            wout[(size_t)(2 * m + 1) * 16384 + p] = f2bf(r);
        }
    } else {
        cnt[tid] = 0;
        __syncthreads();
        int base = (b - NB_CONV - NB_PACK) * 2048;
        #pragma unroll
        for (int k = 0; k < 8; ++k) {
            int e = base + k * 256 + tid;
            if (e < N_EDGES) atomicAdd(&cnt[dst[e] / NPB], 1);
        }
        __syncthreads();
        int c = cnt[tid];
        if (c > 0) atomicAdd(&gbcnt[tid], c);
    }
}

// ---------------------------------------------------------------------------
// CSR build step 2: exclusive scan of the 256 bucket counts (one tiny block).
// ---------------------------------------------------------------------------
__global__ __launch_bounds__(256) void bscan_kernel(const int* __restrict__ gbcnt,
                                                    int* __restrict__ bstart,
                                                    int* __restrict__ bcur) {
    __shared__ int s[NB];
    int tid = threadIdx.x;
    int v = gbcnt[tid];
    s[tid] = v;
    __syncthreads();
    for (int d = 1; d < NB; d <<= 1) {
        int t = (tid >= d) ? s[tid - d] : 0;
        __syncthreads();
        s[tid] += t;
        __syncthreads();
    }
    int incl = s[tid];
    bstart[tid] = incl - v;
    bcur[tid] = incl - v;
    if (tid == NB - 1) bstart[NB] = incl;
}

// ---------------------------------------------------------------------------
// CSR build step 3a: coarse bucket scatter.
// ---------------------------------------------------------------------------
__global__ __launch_bounds__(256) void bucket_scatter(
    const int* __restrict__ src, const int* __restrict__ dst,
    const float* __restrict__ ew, int* __restrict__ bcur,
    uint2* __restrict__ pay) {
    __shared__ int cnt[NB];
    __shared__ int cur[NB];
    int tid = threadIdx.x;
    for (int i = tid; i < NB; i += 256) cnt[i] = 0;
    __syncthreads();
    int base = blockIdx.x * 2048;
    int s[8], d[8], b[8];
    float w[8];
    #pragma unroll
    for (int k = 0; k < 8; ++k) {
        int e = base + k * 256 + tid;
        bool v = e < N_EDGES;
        d[k] = v ? dst[e] : 0;
        s[k] = v ? src[e] : 0;
        w[k] = v ? ew[e] : 0.f;
        b[k] = d[k] / NPB;                 // constant div -> magic mul
        if (v) atomicAdd(&cnt[b[k]], 1);
    }
    __syncthreads();
    for (int i = tid; i < NB; i += 256) {
        int c = cnt[i];
        cur[i] = (c > 0) ? atomicAdd(&bcur[i], c) : 0;
    }
    __syncthreads();
    #pragma unroll
    for (int k = 0; k < 8; ++k) {
        int e = base + k * 256 + tid;
        if (e < N_EDGES) {
            int bk = b[k];
            int p = atomicAdd(&cur[bk], 1);
            unsigned dloc = (unsigned)(d[k] - bk * NPB);
            pay[p] = make_uint2((unsigned)s[k] | (dloc << 17), __float_as_uint(w[k]));
        }
    }
}

// ---------------------------------------------------------------------------
// CSR build step 3b: per-bucket exact sort, in place; also writes offs.
// ---------------------------------------------------------------------------
__global__ __launch_bounds__(256) void bucket_sort(const int* __restrict__ bstart,
                                                   int* __restrict__ offs,
                                                   uint2* __restrict__ pay) {
    __shared__ uint2 lp[BCAP];
    __shared__ int lcnt[NB];
    __shared__ int cur[NPB];
    int b = blockIdx.x;
    int tid = threadIdx.x;
    int n0 = b * NPB;
    int n1 = min(n0 + NPB, N_NODES);
    int nn = n1 - n0;
    int r0 = bstart[b];
    int r1 = bstart[b + 1];
    int cnt = r1 - r0;
    lcnt[tid] = 0;
    __syncthreads();
    for (int i = tid; i < cnt; i += 256) {
        uint2 e = pay[r0 + i];
        if (i < BCAP) lp[i] = e;
        atomicAdd(&lcnt[e.x >> 17], 1);
    }
    __syncthreads();
    int v = lcnt[tid];
    for (int d = 1; d < NB; d <<= 1) {
        int t = (tid >= d) ? lcnt[tid - d] : 0;
        __syncthreads();
        lcnt[tid] += t;
        __syncthreads();
    }
    int excl = lcnt[tid] - v;
    if (tid < nn) {
        offs[n0 + tid] = r0 + excl;
        cur[tid] = excl;
    }
    if (tid == 0) offs[n1] = r1;
    __syncthreads();
    for (int i = tid; i < cnt; i += 256) {
        if (i < BCAP) {
            uint2 e = lp[i];
            int p = atomicAdd(&cur[e.x >> 17], 1);
            if (p < BCAP) pay[r0 + p] = make_uint2(e.x & 0x1FFFFu, e.y);
        }
    }
}

// ---------------------------------------------------------------------------
// Gather-aggregate + GIN combine (fp16 in, fp32 accumulate, fp16 out).
// 32 lanes/node (max TLP), edge loop unrolled x8 for memory-level parallelism.
// ---------------------------------------------------------------------------
__global__ void gather_agg_f16(const ushort* __restrict__ z, const int* __restrict__ offs,
                               const uint2* __restrict__ pay,
                               const float* __restrict__ epsp, int layer,
                               ushort* __restrict__ A) {
    int tid = blockIdx.x * blockDim.x + threadIdx.x;
    int n = tid >> 5;
    if (n >= N_NODES) return;
    int f = (tid & 31) << 2;
    float epsv = 1.0f + epsp[layer];
    int beg = offs[n], end = offs[n + 1];
    ushort4 zi = *(const ushort4*)(z + (size_t)n * D + f);
    float ax = epsv * h2f(zi.x), ay = epsv * h2f(zi.y);
    float az = epsv * h2f(zi.z), aw = epsv * h2f(zi.w);
    int j = beg;
    for (; j + 8 <= end; j += 8) {
        uint2 e[8];
        #pragma unroll
        for (int k = 0; k < 8; ++k) e[k] = pay[j + k];
        ushort4 v[8];
        #pragma unroll
        for (int k = 0; k < 8; ++k) v[k] = *(const ushort4*)(z + (size_t)e[k].x * D + f);
        #pragma unroll
        for (int k = 0; k < 8; ++k) {
            float w = __uint_as_float(e[k].y);
            ax += h2f(v[k].x) * w; ay += h2f(v[k].y) * w;
            az += h2f(v[k].z) * w; aw += h2f(v[k].w) * w;
        }
    }
    for (; j + 4 <= end; j += 4) {
        uint2 e0 = pay[j];
        uint2 e1 = pay[j + 1];
        uint2 e2 = pay[j + 2];
        uint2 e3 = pay[j + 3];
        ushort4 v0 = *(const ushort4*)(z + (size_t)e0.x * D + f);
        ushort4 v1 = *(const ushort4*)(z + (size_t)e1.x * D + f);
        ushort4 v2 = *(const ushort4*)(z + (size_t)e2.x * D + f);
        ushort4 v3 = *(const ushort4*)(z + (size_t)e3.x * D + f);
        float w0 = __uint_as_float(e0.y);
        float w1 = __uint_as_float(e1.y);
        float w2 = __uint_as_float(e2.y);
        float w3 = __uint_as_float(e3.y);
        ax += h2f(v0.x) * w0 + h2f(v1.x) * w1 + h2f(v2.x) * w2 + h2f(v3.x) * w3;
        ay += h2f(v0.y) * w0 + h2f(v1.y) * w1 + h2f(v2.y) * w2 + h2f(v3.y) * w3;
        az += h2f(v0.z) * w0 + h2f(v1.z) * w1 + h2f(v2.z) * w2 + h2f(v3.z) * w3;
        aw += h2f(v0.w) * w0 + h2f(v1.w) * w1 + h2f(v2.w) * w2 + h2f(v3.w) * w3;
    }
    for (; j < end; ++j) {
        uint2 e0 = pay[j];
        ushort4 v0 = *(const ushort4*)(z + (size_t)e0.x * D + f);
        float w0 = __uint_as_float(e0.y);
        ax += h2f(v0.x) * w0; ay += h2f(v0.y) * w0;
        az += h2f(v0.z) * w0; aw += h2f(v0.w) * w0;
    }
    *(ushort4*)(A + (size_t)n * D + f) = make_ushort4(f2h(ax), f2h(ay), f2h(az), f2h(aw));
}

// ---------------------------------------------------------------------------
// Fused GIN MLP — c-split, 64-row blocks (round-9 structure) + W2 register
// prefetch: all 16 W2 fragments are loaded at kernel entry, so their L2
// latency hides under GEMM1 compute and GEMM2 after barrier 1 is pure
// LDS-read + MFMA (T14 issue-early/consume-late). VGPR ~144 still allows
// 3 waves/SIMD = the grid cap (3 blocks/CU x 4 waves) -> no occupancy loss.
// GEMM1 & GEMM2: 2-chain f16 MFMA (W = f16 hi + 2048-scaled f16 lo).
// H in LDS as plain fp16 (17.4 KB/block, 3 barriers as in round 9).
// ---------------------------------------------------------------------------
#define HSTR2 136   // ushorts: 128 + 8 pad -> 272B row stride
template<bool STATS>
__global__ __launch_bounds__(256) void mlp_fused(
    const ushort* __restrict__ A,
    const ushort* __restrict__ W1hi, const ushort* __restrict__ W1lo,
    const float* __restrict__ b1,
    const ushort* __restrict__ W2hi, const ushort* __restrict__ W2lo,
    const float* __restrict__ b2, ushort* __restrict__ Z,
    float* __restrict__ stats) {
    __shared__ ushort Hs[64 * HSTR2];
    int tid = threadIdx.x;
    int lane = tid & 63;
    int wave = tid >> 6;
    int rlo = lane & 15;
    int quad = lane >> 4;
    int blk0 = blockIdx.x * 64;

    const f16x8* W1h = (const f16x8*)W1hi;
    const f16x8* W1l = (const f16x8*)W1lo;
    const f16x8* W2hp = (const f16x8*)W2hi;
    const f16x8* W2lp = (const f16x8*)W2lo;

    // A fragments for all 4 row-frags (all waves load the same tile -> L1)
    f16x8 af[4][4];
    #pragma unroll
    for (int rf = 0; rf < 4; ++rf) {
        int arow = blk0 + rf * 16 + rlo;
        int ar = (arow < N_NODES) ? arow : (N_NODES - 1);
        #pragma unroll
        for (int kc = 0; kc < 4; ++kc) {
            u16x8 raw = *(const u16x8*)(A + (size_t)ar * D + kc * 32 + quad * 8);
            af[rf][kc] = as_f16x8(raw);
        }
    }

    // W2 prefetch: issue ALL GEMM2 weight loads now (no data dependency);
    // latency hides under GEMM1. 16 frags x 4 VGPR = 64 VGPR.
    f16x8 w2h[2][4], w2l[2][4];
    #pragma unroll
    for (int cc = 0; cc < 2; ++cc) {
        int c = 2 * wave + cc;
        #pragma unroll
        for (int kc = 0; kc < 4; ++kc) {
            w2h[cc][kc] = W2hp[(c * 4 + kc) * 64 + lane];
            w2l[cc][kc] = W2lp[(c * 4 + kc) * 64 + lane];
        }
    }

    // GEMM1: wave computes its 2 column-groups for all 4 row-frags;
    // epilogue-1 stores H as plain f16 to LDS.
    #pragma unroll
    for (int cc = 0; cc < 2; ++cc) {
        int c = 2 * wave + cc;
        f32x4 aH[4], aL[4];
        #pragma unroll
        for (int rf = 0; rf < 4; ++rf) {
            aH[rf] = (f32x4){0.f, 0.f, 0.f, 0.f};
            aL[rf] = (f32x4){0.f, 0.f, 0.f, 0.f};
        }
        #pragma unroll
        for (int kc = 0; kc < 4; ++kc) {
            f16x8 wh = W1h[(c * 4 + kc) * 64 + lane];
            f16x8 wl = W1l[(c * 4 + kc) * 64 + lane];
            #pragma unroll
            for (int rf = 0; rf < 4; ++rf) {
                aH[rf] = __builtin_amdgcn_mfma_f32_16x16x32_f16(af[rf][kc], wh, aH[rf], 0, 0, 0);
                aL[rf] = __builtin_amdgcn_mfma_f32_16x16x32_f16(af[rf][kc], wl, aL[rf], 0, 0, 0);
            }
        }
        int col = c * 16 + rlo;
        float bb = b1[col];
        #pragma unroll
        for (int rf = 0; rf < 4; ++rf) {
            #pragma unroll
            for (int r = 0; r < 4; ++r) {
                float v = fmaxf(aH[rf][r] + aL[rf][r] * (1.0f / 2048.0f) + bb, 0.f);
                Hs[(rf * 16 + quad * 4 + r) * HSTR2 + col] = f2h(v);
            }
        }
    }
    __syncthreads();

    // GEMM2: pure LDS-read + MFMA (weights already in registers)
    f32x4 aH2[2][4], aL2[2][4];
    #pragma unroll
    for (int cc = 0; cc < 2; ++cc)
        #pragma unroll
        for (int rf = 0; rf < 4; ++rf) {
            aH2[cc][rf] = (f32x4){0.f, 0.f, 0.f, 0.f};
            aL2[cc][rf] = (f32x4){0.f, 0.f, 0.f, 0.f};
        }

    #pragma unroll
    for (int kc = 0; kc < 4; ++kc) {
        f16x8 a2[4];
        #pragma unroll
        for (int rf = 0; rf < 4; ++rf) {
            a2[rf] = as_f16x8(*(const u16x8*)&Hs[(rf * 16 + rlo) * HSTR2 + kc * 32 + quad * 8]);
        }
        #pragma unroll
        for (int cc = 0; cc < 2; ++cc) {
            #pragma unroll
            for (int rf = 0; rf < 4; ++rf) {
                aH2[cc][rf] = __builtin_amdgcn_mfma_f32_16x16x32_f16(a2[rf], w2h[cc][kc], aH2[cc][rf], 0, 0, 0);
                aL2[cc][rf] = __builtin_amdgcn_mfma_f32_16x16x32_f16(a2[rf], w2l[cc][kc], aL2[cc][rf], 0, 0, 0);
            }
        }
    }
    __syncthreads();   // all LDS reads done before epilogue-2 overwrites

    // epilogue 2: relu(acc + b2) -> fp16 in Hs, fused stats (fp32 pre-round)
    #pragma unroll
    for (int cc = 0; cc < 2; ++cc) {
        int c = 2 * wave + cc;
        int col = c * 16 + rlo;
        float bb = b2[col];
        float s = 0.f, s2 = 0.f;
        #pragma unroll
        for (int rf = 0; rf < 4; ++rf) {
            #pragma unroll
            for (int r = 0; r < 4; ++r) {
                float v = fmaxf(aH2[cc][rf][r] + aL2[cc][rf][r] * (1.0f / 2048.0f) + bb, 0.f);
                Hs[(rf * 16 + quad * 4 + r) * HSTR2 + col] = f2h(v);
                if (STATS) {
                    float m = (blk0 + rf * 16 + quad * 4 + r < N_NODES) ? v : 0.f;
                    s += m;
                    s2 += m * m;
                }
            }
        }
        if (STATS) {
            s  += __shfl_xor(s, 16, 64);
            s  += __shfl_xor(s, 32, 64);
            s2 += __shfl_xor(s2, 16, 64);
            s2 += __shfl_xor(s2, 32, 64);
            if (quad == 0) {
                atomicAdd(&stats[col], s);
                atomicAdd(&stats[D + col], s2);
            }
        }
    }
    __syncthreads();

    // coalesced fp16 copy-out: wave w writes rows [16w, 16w+16)
    #pragma unroll
    for (int it = 0; it < 4; ++it) {
        int r = wave * 16 + it * 4 + quad;
        int grow = blk0 + r;
        if (grow < N_NODES) {
            u16x8 vv = *(const u16x8*)&Hs[r * HSTR2 + rlo * 8];
            *(u16x8*)(Z + (size_t)grow * D + rlo * 8) = vv;
        }
    }
}

// ---------------------------------------------------------------------------
// Final: zn = BN(Z)*gamma+beta (fp32 out), p = PReLU(zn @ Wp + bp) (fp32 out)
// ---------------------------------------------------------------------------
#define PSTR 132   // floats
__global__ __launch_bounds__(256) void bn_proj(
    const ushort* __restrict__ Z, const float* __restrict__ stats,
    const float* __restrict__ gamma, const float* __restrict__ beta,
    const ushort* __restrict__ Wphi, const ushort* __restrict__ Wplo,
    const float* __restrict__ bp, const float* __restrict__ prelu_a,
    float* __restrict__ zn_out, float* __restrict__ p_out) {
    __shared__ float sc_s[D];
    __shared__ float sh_s[D];
    __shared__ float Ps[4][16 * PSTR];
    int tid = threadIdx.x;
    int lane = tid & 63;
    int wave = tid >> 6;
    int rlo = lane & 15;
    int quad = lane >> 4;

    if (tid < D) {
        float m = stats[tid] * (1.0f / N_NODES);
        float v = stats[D + tid] * (1.0f / N_NODES) - m * m;
        float rs = rsqrtf(v + BN_EPS);
        float sc = rs * gamma[tid];
        sc_s[tid] = sc;
        sh_s[tid] = beta[tid] - m * sc;
    }
    __syncthreads();

    int row0 = blockIdx.x * 64 + wave * 16;
    int arow = row0 + rlo;
    int ar = (arow < N_NODES) ? arow : (N_NODES - 1);

    const bf16x8* Wh = (const bf16x8*)Wphi;
    const bf16x8* Wl = (const bf16x8*)Wplo;

    // load Z frags, apply BN -> zn (fp32 store + split-bf16 a-frags)
    bf16x8 ahi[4], alo[4];
    #pragma unroll
    for (int kc = 0; kc < 4; ++kc) {
        u16x8 raw = *(const u16x8*)(Z + (size_t)ar * D + kc * 32 + quad * 8);
        float zn[8];
        #pragma unroll
        for (int j = 0; j < 8; ++j) {
            int k = kc * 32 + quad * 8 + j;
            zn[j] = sc_s[k] * h2f(raw[j]) + sh_s[k];
            unsigned short h = f2bf(zn[j]);
            ahi[kc][j] = (short)h;
            alo[kc][j] = (short)f2bf(zn[j] - bf2f(h));
        }
        if (arow < N_NODES) {
            float* dst = zn_out + (size_t)arow * D + kc * 32 + quad * 8;
            *(float4*)dst = make_float4(zn[0], zn[1], zn[2], zn[3]);
            *(float4*)(dst + 4) = make_float4(zn[4], zn[5], zn[6], zn[7]);
        }
    }

    f32x4 acc[8];
    #pragma unroll
    for (int c = 0; c < 8; ++c) acc[c] = (f32x4){0.f, 0.f, 0.f, 0.f};
    #pragma unroll
    for (int c = 0; c < 8; ++c) {
        #pragma unroll
        for (int kc = 0; kc < 4; ++kc) {
            bf16x8 wh = Wh[(c * 4 + kc) * 64 + lane];
            bf16x8 wl = Wl[(c * 4 + kc) * 64 + lane];
            acc[c] = __builtin_amdgcn_mfma_f32_16x16x32_bf16(alo[kc], wh, acc[c], 0, 0, 0);
            acc[c] = __builtin_amdgcn_mfma_f32_16x16x32_bf16(ahi[kc], wl, acc[c], 0, 0, 0);
            acc[c] = __builtin_amdgcn_mfma_f32_16x16x32_bf16(ahi[kc], wh, acc[c], 0, 0, 0);
        }
    }

    float aP = prelu_a[0];
    #pragma unroll
    for (int c = 0; c < 8; ++c) {
        int col = c * 16 + rlo;
        float bb = bp[col];
        #pragma unroll
        for (int r = 0; r < 4; ++r) {
            float v = acc[c][r] + bb;
            v = (v >= 0.f) ? v : aP * v;
            Ps[wave][(quad * 4 + r) * PSTR + col] = v;
        }
    }
    __syncthreads();
    #pragma unroll
    for (int p2 = 0; p2 < 8; ++p2) {
        int r = p2 * 2 + (lane >> 5);
        int grow = row0 + r;
        if (grow < N_NODES) {
            *(float4*)(p_out + (size_t)grow * D + (lane & 31) * 4) =
                *(const float4*)&Ps[wave][r * PSTR + (lane & 31) * 4];
        }
    }
}

// ---------------------------------------------------------------------------
extern "C" void kernel_launch(void* const* d_in, const int* in_sizes, int n_in,
                              void* d_out, int out_size, void* d_ws, size_t ws_size,
                              hipStream_t stream) {
    (void)in_sizes; (void)n_in; (void)out_size; (void)ws_size;
    const float* x     = (const float*)d_in[0];
    const float* ew    = (const float*)d_in[1];
    const float* W1s   = (const float*)d_in[2];
    const float* b1s   = (const float*)d_in[3];
    const float* W2s   = (const float*)d_in[4];
    const float* b2s   = (const float*)d_in[5];
    const float* eps   = (const float*)d_in[6];
    const float* gamma = (const float*)d_in[7];
    const float* beta  = (const float*)d_in[8];
    const float* Wp    = (const float*)d_in[9];
    const float* bp    = (const float*)d_in[10];
    const float* pa    = (const float*)d_in[11];
    const int*   ei    = (const int*)d_in[12];
    const int* srcp = ei;
    const int* dstp = ei + N_EDGES;

    // workspace layout (bytes):
    char* wsb = (char*)d_ws;
    float*  stats  = (float*)wsb;                 wsb += 1024;           // 256 f
    int*    offs   = (int*)wsb;                   wsb += 200016;         // 50004 i
    int*    bcur   = (int*)wsb;                   // 256 i
    int*    gbcnt  = bcur + 256;                  // 256 i
    int*    bstart = bcur + 512;                  wsb += 200016;         // 257 i
    uint2*  pay    = (uint2*)wsb;                 wsb += 6400000;        // 800000 uint2
    ushort* Wpk    = (ushort*)wsb;                wsb += 14 * 16384 * 2; // split weights
    ushort* Xh     = (ushort*)wsb;                wsb += (size_t)ND * 2; // x in fp16
    ushort* Ah     = (ushort*)wsb;                wsb += (size_t)ND * 2; // gather out fp16
    ushort* Zh     = (ushort*)wsb;                wsb += (size_t)ND * 2; // layer out fp16

    float* out_zn = (float*)d_out;
    float* out_p  = out_zn + ND;

    hipMemsetAsync(stats, 0, 256 * sizeof(float), stream);
    hipMemsetAsync(gbcnt, 0, NB * sizeof(int), stream);

    prologue<<<NB_CONV + NB_PACK + NB_HIST, 256, 0, stream>>>(
        x, Xh, W1s, W2s, Wp, Wpk, dstp, gbcnt);

    bscan_kernel<<<1, 256, 0, stream>>>(gbcnt, bstart, bcur);
    bucket_scatter<<<(N_EDGES + 2047) / 2048, 256, 0, stream>>>(srcp, dstp, ew, bcur, pay);
    bucket_sort<<<NB, 256, 0, stream>>>(bstart, offs, pay);

    int mgrid = (N_NODES + 63) / 64;
    const ushort* zin = Xh;
    for (int l = 0; l < 3; ++l) {
        gather_agg_f16<<<(N_NODES * 32 + 255) / 256, 256, 0, stream>>>(zin, offs, pay, eps, l, Ah);
        if (l < 2) {
            mlp_fused<false><<<mgrid, 256, 0, stream>>>(Ah,
                Wpk + (size_t)(2 * l) * 16384,       Wpk + (size_t)(2 * l + 1) * 16384, b1s + (size_t)l * D,
                Wpk + (size_t)(2 * (3 + l)) * 16384, Wpk + (size_t)(2 * (3 + l) + 1) * 16384, b2s + (size_t)l * D,
                Zh, stats);
        } else {
            mlp_fused<true><<<mgrid, 256, 0, stream>>>(Ah,
                Wpk + (size_t)(2 * l) * 16384,       Wpk + (size_t)(2 * l + 1) * 16384, b1s + (size_t)l * D,
                Wpk + (size_t)(2 * (3 + l)) * 16384, Wpk + (size_t)(2 * (3 + l) + 1) * 16384, b2s + (size_t)l * D,
                Zh, stats);
        }
        zin = Zh;
    }
    bn_proj<<<mgrid, 256, 0, stream>>>(Zh, stats, gamma, beta,
        Wpk + (size_t)12 * 16384, Wpk + (size_t)13 * 16384, bp, pa, out_zn, out_p);
}